// Round 1
// baseline (11025.626 us; speedup 1.0000x reference)
//
#include <hip/hip_runtime.h>

#define S_LEN 128
#define B_N   1024
#define T_LEN 96
#define E_DIM 64
#define HH    100
#define H_DIM 200
#define ACT_D 32
#define FLD_D 8
#define ATT_D 200
#define DEC_IN 440          // 32 + 200 + 8 + 200
#define KTOT  640           // DEC_IN + H_DIM
#define G4H   800           // 4*H
#define G4HH  400           // 4*HH

typedef unsigned int  u32;
typedef unsigned short u16;

static __device__ __forceinline__ float lo_bf(u32 u){ union{u32 i; float f;}v; v.i = u<<16; return v.f; }
static __device__ __forceinline__ float hi_bf(u32 u){ union{u32 i; float f;}v; v.i = u & 0xffff0000u; return v.f; }
static __device__ __forceinline__ u16 f2bf(float f){
  union{float f; u32 i;} v; v.f = f;
  u32 r = v.i + 0x7fffu + ((v.i >> 16) & 1u);
  return (u16)(r >> 16);
}
static __device__ __forceinline__ float sigf(float x){
  x = fminf(30.f, fmaxf(-30.f, x));
  return 1.f/(1.f + __expf(-x));
}
static __device__ __forceinline__ float tanhf_(float x){
  x = fminf(15.f, fmaxf(-15.f, x));
  float e = __expf(-2.f*x);
  return (1.f - e)/(1.f + e);
}

// Repack weights: src element (k=reduction, c=output col) at src[k*sk + c*sc]
// -> bf16 "quad" layout: dst[(k>>2)*(4*C) + 4*c + (k&3)]  (K must be mult of 4)
__global__ void k_prep(u16* __restrict__ dst, const float* __restrict__ src,
                       int K, int C, int sk, int sc)
{
  int idx = blockIdx.x*256 + threadIdx.x;
  if (idx >= K*C) return;
  int k = idx / C, c = idx - k*C;
  dst[(size_t)(k>>2)*(4*C) + 4*c + (k&3)] = f2bf(src[(size_t)k*sk + (size_t)c*sc]);
}

// Bi-LSTM encoder, fused: embedding gather + input GEMM + recurrence.
// Grid 256: blocks 0..127 forward (8 batch rows each), 128..255 backward.
__global__ __launch_bounds__(512) void k_encoder(
    const int* __restrict__ sentences, const float* __restrict__ src_emb,
    const float* __restrict__ b_f, const float* __restrict__ b_b,
    const uint2* __restrict__ wihF, const uint2* __restrict__ whhF,
    const uint2* __restrict__ wihB, const uint2* __restrict__ whhB,
    u16* __restrict__ enc,                 // [B][S][200] bf16
    float* __restrict__ hTf, float* __restrict__ cTf,
    float* __restrict__ hTb, float* __restrict__ cTb)
{
  const int tid = threadIdx.x;
  const int dir = blockIdx.x >> 7;
  const int bg  = blockIdx.x & 127;
  const int b0  = bg * 8;

  __shared__ alignas(16) float xs[8][E_DIM];
  __shared__ alignas(16) float hs[8][HH];
  __shared__ alignas(16) float zs[8][G4HH];

  const uint2* wih = dir ? wihB : wihF;
  const uint2* whh = dir ? whhB : whhF;
  const float* bias = dir ? b_b : b_f;

  for (int idx = tid; idx < 8*HH; idx += 512) ((float*)hs)[idx] = 0.f;
  float c0r = 0.f, c1r = 0.f;

  const int col = tid;                 // gate column, active if < 400
  const bool act = (col < G4HH);
  const float bias0 = act ? bias[col] : 0.f;

  __syncthreads();

  for (int step = 0; step < S_LEN; ++step) {
    const int s = dir ? (S_LEN-1-step) : step;
    {
      int r = tid >> 6, e = tid & 63;          // 512 == 8*64
      int tok = sentences[s*B_N + (b0 + r)];
      xs[r][e] = src_emb[(size_t)tok*E_DIM + e];
    }
    __syncthreads();

    if (act) {
      float acc[8];
      #pragma unroll
      for (int r = 0; r < 8; ++r) acc[r] = bias0;
      #pragma unroll 2
      for (int k4 = 0; k4 < E_DIM/4; ++k4) {
        uint2 u = wih[k4*G4HH + col];
        float w0 = lo_bf(u.x), w1 = hi_bf(u.x), w2 = lo_bf(u.y), w3 = hi_bf(u.y);
        #pragma unroll
        for (int r = 0; r < 8; ++r) {
          float4 xv = *(const float4*)&xs[r][4*k4];
          acc[r] += xv.x*w0 + xv.y*w1 + xv.z*w2 + xv.w*w3;
        }
      }
      #pragma unroll 2
      for (int k4 = 0; k4 < HH/4; ++k4) {
        uint2 u = whh[k4*G4HH + col];
        float w0 = lo_bf(u.x), w1 = hi_bf(u.x), w2 = lo_bf(u.y), w3 = hi_bf(u.y);
        #pragma unroll
        for (int r = 0; r < 8; ++r) {
          float4 hv = *(const float4*)&hs[r][4*k4];
          acc[r] += hv.x*w0 + hv.y*w1 + hv.z*w2 + hv.w*w3;
        }
      }
      #pragma unroll
      for (int r = 0; r < 8; ++r) zs[r][col] = acc[r];
    }
    __syncthreads();

    // LSTM cell: 800 (r,j) slots; slot0=tid, slot1=tid+512 (tid<288)
    {
      int r = tid / HH, j = tid - r*HH;
      float c = sigf(zs[r][HH+j])*c0r + sigf(zs[r][j])*tanhf_(zs[r][2*HH+j]);
      float h = sigf(zs[r][3*HH+j])*tanhf_(c);
      c0r = c;
      hs[r][j] = h;
      enc[((size_t)(b0+r)*S_LEN + s)*H_DIM + dir*HH + j] = f2bf(h);
      if (tid < 8*HH - 512) {
        int idx2 = tid + 512;
        int r2 = idx2 / HH, j2 = idx2 - r2*HH;
        float c2 = sigf(zs[r2][HH+j2])*c1r + sigf(zs[r2][j2])*tanhf_(zs[r2][2*HH+j2]);
        float h2 = sigf(zs[r2][3*HH+j2])*tanhf_(c2);
        c1r = c2;
        hs[r2][j2] = h2;
        enc[((size_t)(b0+r2)*S_LEN + s)*H_DIM + dir*HH + j2] = f2bf(h2);
      }
    }
    __syncthreads();
  }

  float* hT = dir ? hTb : hTf;
  float* cT = dir ? cTb : cTf;
  {
    int r = tid / HH, j = tid - r*HH;
    hT[(b0+r)*HH + j] = hs[r][j];
    cT[(b0+r)*HH + j] = c0r;
    if (tid < 8*HH - 512) {
      int idx2 = tid + 512; int r2 = idx2 / HH, j2 = idx2 - r2*HH;
      hT[(b0+r2)*HH + j2] = hs[r2][j2];
      cT[(b0+r2)*HH + j2] = c1r;
    }
  }
}

// Decoder: persistent, 4 batch rows per block, 96 sequential steps.
__global__ __launch_bounds__(512) void k_decoder(
  const int* __restrict__ is_prod, const int* __restrict__ prod_ids,
  const int* __restrict__ prim_ids, const int* __restrict__ field_ids,
  const int* __restrict__ parent_t,
  const float* __restrict__ actprod_emb, const float* __restrict__ prim_emb,
  const float* __restrict__ field_emb, const float* __restrict__ b_d,
  const uint2* __restrict__ wall, const uint2* __restrict__ wattn, const uint2* __restrict__ wav,
  const u16* __restrict__ enc,
  const float* __restrict__ hTf, const float* __restrict__ cTf,
  const float* __restrict__ hTb, const float* __restrict__ cTb,
  float* __restrict__ Hbuf, float* __restrict__ out)
{
  const int tid = threadIdx.x;
  const int b0 = blockIdx.x * 4;

  __shared__ alignas(16) float xs[4][KTOT];   // [a(32) s_att(200) nft(8) parent(200) h(200)]
  __shared__ alignas(16) float zs[4][G4H];
  __shared__ alignas(16) float gs[4][H_DIM];
  __shared__ alignas(16) float ctx[4][H_DIM];
  __shared__ float sc[4][S_LEN];
  __shared__ float aw[4][S_LEN];
  __shared__ float den[4];

  // init: s_att region = 0 (s_att0)
  for (int idx = tid; idx < 4*ATT_D; idx += 512) {
    int r = idx / ATT_D, k = idx - r*ATT_D;
    xs[r][ACT_D + k] = 0.f;
  }
  // h0 per torch h0.view(-1,H) quirk
  for (int idx = tid; idx < 4*H_DIM; idx += 512) {
    int r = idx / H_DIM, j = idx - r*H_DIM;
    int b = b0 + r;
    float v;
    if (b < 512) v = (j < HH) ? hTf[(2*b)*HH + j] : hTf[(2*b+1)*HH + (j-HH)];
    else { int bb = b-512; v = (j < HH) ? hTb[(2*bb)*HH + j] : hTb[(2*bb+1)*HH + (j-HH)]; }
    xs[r][DEC_IN + j] = v;
  }
  float c0r = 0.f, c1r = 0.f;
  {
    int r = tid / H_DIM, j = tid - r*H_DIM; int b = b0 + r;
    if (b < 512) c0r = (j < HH) ? cTf[(2*b)*HH + j] : cTf[(2*b+1)*HH + (j-HH)];
    else { int bb = b-512; c0r = (j < HH) ? cTb[(2*bb)*HH + j] : cTb[(2*bb+1)*HH + (j-HH)]; }
    if (tid < G4H - 512) {
      int idx2 = tid + 512; int r2 = idx2 / H_DIM, j2 = idx2 - r2*H_DIM; int b2 = b0 + r2;
      if (b2 < 512) c1r = (j2 < HH) ? cTf[(2*b2)*HH + j2] : cTf[(2*b2+1)*HH + (j2-HH)];
      else { int bb = b2-512; c1r = (j2 < HH) ? cTb[(2*bb)*HH + j2] : cTb[(2*bb+1)*HH + (j2-HH)]; }
    }
  }
  const int zc0 = tid;
  const bool hz1 = (tid < G4H - 512);     // tid < 288
  const int zc1 = hz1 ? (tid + 512) : tid;
  const float bd0 = b_d[zc0];
  const float bd1 = b_d[zc1];

  __syncthreads();

  for (int t = 0; t < T_LEN; ++t) {
    // ---- stage a_tm1 / nft / parent (s_att + h persist in LDS). t==0 -> zeros.
    for (int idx = tid; idx < 4*DEC_IN; idx += 512) {
      int r = idx / DEC_IN, k = idx - r*DEC_IN;
      if (k >= ACT_D && k < ACT_D + ATT_D) continue;
      float v = 0.f;
      if (t > 0) {
        int b = b0 + r;
        if (k < ACT_D) {
          v = (is_prod[t*B_N + b] == 1)
            ? actprod_emb[prod_ids[t*B_N + b]*ACT_D + k]
            : prim_emb[prim_ids[t*B_N + b]*ACT_D + k];
        } else if (k < ACT_D + ATT_D + FLD_D) {
          v = field_emb[field_ids[t*B_N + b]*FLD_D + (k - ACT_D - ATT_D)];
        } else {
          int pt = parent_t[t*B_N + b];
          v = Hbuf[((size_t)pt*B_N + b)*H_DIM + (k - (ACT_D+ATT_D+FLD_D))];
        }
      }
      xs[r][k] = v;
    }
    __syncthreads();

    // ---- z = [inp,h] @ Wall^T + b_d   (K = 640, bf16 weights, fp32 acc)
    float a00=bd0, a10=bd0, a20=bd0, a30=bd0;
    float a01=bd1, a11=bd1, a21=bd1, a31=bd1;
    #pragma unroll 2
    for (int k4 = 0; k4 < KTOT/4; ++k4) {
      uint2 u0 = wall[k4*G4H + zc0];
      uint2 u1 = wall[k4*G4H + zc1];
      float p0 = lo_bf(u0.x), p1 = hi_bf(u0.x), p2 = lo_bf(u0.y), p3 = hi_bf(u0.y);
      float q0 = lo_bf(u1.x), q1 = hi_bf(u1.x), q2 = lo_bf(u1.y), q3 = hi_bf(u1.y);
      float4 x0 = *(const float4*)&xs[0][4*k4];
      float4 x1 = *(const float4*)&xs[1][4*k4];
      float4 x2 = *(const float4*)&xs[2][4*k4];
      float4 x3 = *(const float4*)&xs[3][4*k4];
      a00 += x0.x*p0 + x0.y*p1 + x0.z*p2 + x0.w*p3;
      a10 += x1.x*p0 + x1.y*p1 + x1.z*p2 + x1.w*p3;
      a20 += x2.x*p0 + x2.y*p1 + x2.z*p2 + x2.w*p3;
      a30 += x3.x*p0 + x3.y*p1 + x3.z*p2 + x3.w*p3;
      a01 += x0.x*q0 + x0.y*q1 + x0.z*q2 + x0.w*q3;
      a11 += x1.x*q0 + x1.y*q1 + x1.z*q2 + x1.w*q3;
      a21 += x2.x*q0 + x2.y*q1 + x2.z*q2 + x2.w*q3;
      a31 += x3.x*q0 + x3.y*q1 + x3.z*q2 + x3.w*q3;
    }
    zs[0][zc0]=a00; zs[1][zc0]=a10; zs[2][zc0]=a20; zs[3][zc0]=a30;
    if (hz1) { zs[0][zc1]=a01; zs[1][zc1]=a11; zs[2][zc1]=a21; zs[3][zc1]=a31; }
    __syncthreads();

    // ---- LSTM cell (gate order i,f,g,o)
    {
      int r = tid / H_DIM, j = tid - r*H_DIM;
      float c = sigf(zs[r][H_DIM+j])*c0r + sigf(zs[r][j])*tanhf_(zs[r][2*H_DIM+j]);
      float h = sigf(zs[r][3*H_DIM+j])*tanhf_(c);
      c0r = c;
      xs[r][DEC_IN + j] = h;
      Hbuf[((size_t)t*B_N + (b0+r))*H_DIM + j] = h;
      if (hz1) {
        int idx2 = tid + 512; int r2 = idx2 / H_DIM, j2 = idx2 - r2*H_DIM;
        float c2 = sigf(zs[r2][H_DIM+j2])*c1r + sigf(zs[r2][j2])*tanhf_(zs[r2][2*H_DIM+j2]);
        float h2 = sigf(zs[r2][3*H_DIM+j2])*tanhf_(c2);
        c1r = c2;
        xs[r2][DEC_IN + j2] = h2;
        Hbuf[((size_t)t*B_N + (b0+r2))*H_DIM + j2] = h2;
      }
    }
    __syncthreads();

    // ---- g = W_attn^T h  (so scores = enc . g, no enc_att tensor)
    {
      int r = tid / H_DIM, k = tid - r*H_DIM;
      float acc = 0.f;
      #pragma unroll 2
      for (int j4 = 0; j4 < H_DIM/4; ++j4) {
        uint2 u = wattn[j4*H_DIM + k];
        float4 hv = *(const float4*)&xs[r][DEC_IN + 4*j4];
        acc += hv.x*lo_bf(u.x) + hv.y*hi_bf(u.x) + hv.z*lo_bf(u.y) + hv.w*hi_bf(u.y);
      }
      gs[r][k] = acc;
      if (hz1) {
        int idx2 = tid + 512; int r2 = idx2 / H_DIM, k2 = idx2 - r2*H_DIM;
        float acc2 = 0.f;
        #pragma unroll 2
        for (int j4 = 0; j4 < H_DIM/4; ++j4) {
          uint2 u = wattn[j4*H_DIM + k2];
          float4 hv = *(const float4*)&xs[r2][DEC_IN + 4*j4];
          acc2 += hv.x*lo_bf(u.x) + hv.y*hi_bf(u.x) + hv.z*lo_bf(u.y) + hv.w*hi_bf(u.y);
        }
        gs[r2][k2] = acc2;
      }
    }
    __syncthreads();

    // ---- scores[b,s] = enc[b,s,:] . g[b]
    {
      int r = tid >> 7, s = tid & 127;
      int b = b0 + r;
      const uint2* ep = (const uint2*)(enc + ((size_t)b*S_LEN + s)*H_DIM);
      float acc = 0.f;
      #pragma unroll 4
      for (int k4 = 0; k4 < H_DIM/4; ++k4) {
        uint2 u = ep[k4];
        float4 gv = *(const float4*)&gs[r][4*k4];
        acc += gv.x*lo_bf(u.x) + gv.y*hi_bf(u.x) + gv.z*lo_bf(u.y) + gv.w*hi_bf(u.y);
      }
      sc[r][s] = acc;
    }
    __syncthreads();

    // ---- softmax (max-subtracted)
    {
      int r = tid >> 7, s = tid & 127;
      float m = -1e30f;
      for (int ss = 0; ss < S_LEN; ++ss) m = fmaxf(m, sc[r][ss]);
      aw[r][s] = __expf(sc[r][s] - m);
    }
    __syncthreads();
    if (tid < 4) {
      float d = 0.f;
      for (int ss = 0; ss < S_LEN; ++ss) d += aw[tid][ss];
      den[tid] = d;
    }
    __syncthreads();

    // ---- ctx = softmax(scores) . enc   (200 threads: 4 rows x 50 quads)
    if (tid < 200) {
      int r = tid / 50, kq = tid - r*50;
      int b = b0 + r;
      const uint2* ep = (const uint2*)(enc + (size_t)b*S_LEN*H_DIM) + kq;
      float acc0=0.f, acc1=0.f, acc2=0.f, acc3=0.f;
      #pragma unroll 4
      for (int s = 0; s < S_LEN; ++s) {
        uint2 u = ep[(size_t)s*(H_DIM/4)];
        float w = aw[r][s];
        acc0 += w*lo_bf(u.x); acc1 += w*hi_bf(u.x);
        acc2 += w*lo_bf(u.y); acc3 += w*hi_bf(u.y);
      }
      float rd = 1.f/den[r];
      ctx[r][4*kq+0] = acc0*rd;
      ctx[r][4*kq+1] = acc1*rd;
      ctx[r][4*kq+2] = acc2*rd;
      ctx[r][4*kq+3] = acc3*rd;
    }
    __syncthreads();

    // ---- s_att = tanh([ctx,h] @ W_av^T); write out + persist for next step
    {
      int r = tid / H_DIM, j = tid - r*H_DIM;
      float acc = 0.f;
      #pragma unroll 2
      for (int k4 = 0; k4 < 50; ++k4) {
        uint2 u = wav[k4*H_DIM + j];
        float4 cv = *(const float4*)&ctx[r][4*k4];
        acc += cv.x*lo_bf(u.x) + cv.y*hi_bf(u.x) + cv.z*lo_bf(u.y) + cv.w*hi_bf(u.y);
      }
      #pragma unroll 2
      for (int k4 = 50; k4 < 100; ++k4) {
        uint2 u = wav[k4*H_DIM + j];
        float4 hv = *(const float4*)&xs[r][DEC_IN + 4*(k4-50)];
        acc += hv.x*lo_bf(u.x) + hv.y*hi_bf(u.x) + hv.z*lo_bf(u.y) + hv.w*hi_bf(u.y);
      }
      float sa = tanhf_(acc);
      out[((size_t)t*B_N + (b0+r))*H_DIM + j] = sa;
      xs[r][ACT_D + j] = sa;
      if (hz1) {
        int idx2 = tid + 512; int r2 = idx2 / H_DIM, j2 = idx2 - r2*H_DIM;
        float acc2 = 0.f;
        #pragma unroll 2
        for (int k4 = 0; k4 < 50; ++k4) {
          uint2 u = wav[k4*H_DIM + j2];
          float4 cv = *(const float4*)&ctx[r2][4*k4];
          acc2 += cv.x*lo_bf(u.x) + cv.y*hi_bf(u.x) + cv.z*lo_bf(u.y) + cv.w*hi_bf(u.y);
        }
        #pragma unroll 2
        for (int k4 = 50; k4 < 100; ++k4) {
          uint2 u = wav[k4*H_DIM + j2];
          float4 hv = *(const float4*)&xs[r2][DEC_IN + 4*(k4-50)];
          acc2 += hv.x*lo_bf(u.x) + hv.y*hi_bf(u.x) + hv.z*lo_bf(u.y) + hv.w*hi_bf(u.y);
        }
        float sa2 = tanhf_(acc2);
        out[((size_t)t*B_N + (b0+r2))*H_DIM + j2] = sa2;
        xs[r2][ACT_D + j2] = sa2;
      }
    }
    __syncthreads();
  }
}

extern "C" void kernel_launch(void* const* d_in, const int* in_sizes, int n_in,
                              void* d_out, int out_size, void* d_ws, size_t ws_size,
                              hipStream_t stream)
{
  const int*   sentences = (const int*)  d_in[0];
  const int*   is_prod   = (const int*)  d_in[1];
  const int*   prod_ids  = (const int*)  d_in[2];
  const int*   prim_ids  = (const int*)  d_in[3];
  const int*   field_ids = (const int*)  d_in[4];
  const int*   parent_t  = (const int*)  d_in[5];
  const float* src_emb   = (const float*)d_in[6];
  const float* actprod   = (const float*)d_in[7];
  const float* prim_emb  = (const float*)d_in[8];
  const float* field_emb = (const float*)d_in[9];
  const float* Wih_f = (const float*)d_in[10];
  const float* Whh_f = (const float*)d_in[11];
  const float* b_f   = (const float*)d_in[12];
  const float* Wih_b = (const float*)d_in[13];
  const float* Whh_b = (const float*)d_in[14];
  const float* b_b   = (const float*)d_in[15];
  const float* Wih_d = (const float*)d_in[16];
  const float* Whh_d = (const float*)d_in[17];
  const float* b_d   = (const float*)d_in[18];
  const float* W_attn= (const float*)d_in[19];
  const float* W_av  = (const float*)d_in[20];
  (void)in_sizes; (void)n_in; (void)out_size; (void)ws_size;

  char* ws = (char*)d_ws;
  size_t off = 0;
  auto take = [&](size_t bytes) -> void* {
    void* p = ws + off;
    off = (off + bytes + 255) & ~(size_t)255;
    return p;
  };
  u16* wihF = (u16*)take((size_t)64*400*2);
  u16* whhF = (u16*)take((size_t)100*400*2);
  u16* wihB = (u16*)take((size_t)64*400*2);
  u16* whhB = (u16*)take((size_t)100*400*2);
  u16* wall = (u16*)take((size_t)640*800*2);
  u16* wattn= (u16*)take((size_t)200*200*2);
  u16* wav  = (u16*)take((size_t)400*200*2);
  u16* enc  = (u16*)take((size_t)1024*128*200*2);
  float* hTf = (float*)take((size_t)1024*100*4);
  float* cTf = (float*)take((size_t)1024*100*4);
  float* hTb = (float*)take((size_t)1024*100*4);
  float* cTb = (float*)take((size_t)1024*100*4);
  float* Hbuf= (float*)take((size_t)96*1024*200*4);
  float* outp= (float*)d_out;

  auto prep = [&](u16* dst, const float* src, int K, int C, int sk, int sc){
    int n = K*C;
    k_prep<<<(n+255)/256, 256, 0, stream>>>(dst, src, K, C, sk, sc);
  };
  prep(wihF, Wih_f, 64, 400, 1, 64);
  prep(whhF, Whh_f, 100, 400, 1, 100);
  prep(wihB, Wih_b, 64, 400, 1, 64);
  prep(whhB, Whh_b, 100, 400, 1, 100);
  prep(wall,            Wih_d, 440, 800, 1, 440);   // k = 0..439 (a|s_att|nft|parent)
  prep(wall + 440*800,  Whh_d, 200, 800, 1, 200);   // k = 440..639 (h)
  prep(wattn, W_attn, 200, 200, 200, 1);            // g[k] = sum_j W_attn[j][k] h[j]
  prep(wav,   W_av,   400, 200, 1, 400);

  k_encoder<<<256, 512, 0, stream>>>(sentences, src_emb, b_f, b_b,
      (const uint2*)wihF, (const uint2*)whhF, (const uint2*)wihB, (const uint2*)whhB,
      enc, hTf, cTf, hTb, cTb);

  k_decoder<<<256, 512, 0, stream>>>(is_prod, prod_ids, prim_ids, field_ids, parent_t,
      actprod, prim_emb, field_emb, b_d,
      (const uint2*)wall, (const uint2*)wattn, (const uint2*)wav,
      enc, hTf, cTf, hTb, cTb, Hbuf, outp);
}

// Round 2
// 8000.520 us; speedup vs baseline: 1.3781x; 1.3781x over previous
//
#include <hip/hip_runtime.h>

#define S_LEN 128
#define B_N   1024
#define T_LEN 96
#define E_DIM 64
#define HH    100
#define H_DIM 200
#define ACT_D 32
#define FLD_D 8
#define ATT_D 200
#define DEC_IN 440          // 32 + 200 + 8 + 200
#define KTOT  640           // DEC_IN + H_DIM
#define G4H   800           // 4*H
#define G4HH  400           // 4*HH
#define ENC_LD 224          // enc row stride (f16), 200 + pad to 7*32
#define KH_PAD 224          // h K-pad for g-MFMA
#define KC_PAD 416          // [ctx|h] K-pad for s_att MFMA
#define NCOL_PAD 208        // 13*16 column pad for wattn/wav

typedef unsigned int  u32;
typedef unsigned short u16;
typedef _Float16 f16;
typedef _Float16 f16x8 __attribute__((ext_vector_type(8)));
typedef float    f32x4 __attribute__((ext_vector_type(4)));

#define MFMA16(a,b,c) __builtin_amdgcn_mfma_f32_16x16x32_f16((a),(b),(c),0,0,0)

static __device__ __forceinline__ float lo_bf(u32 u){ union{u32 i; float f;}v; v.i = u<<16; return v.f; }
static __device__ __forceinline__ float hi_bf(u32 u){ union{u32 i; float f;}v; v.i = u & 0xffff0000u; return v.f; }
static __device__ __forceinline__ float sigf(float x){
  x = fminf(30.f, fmaxf(-30.f, x));
  return 1.f/(1.f + __expf(-x));
}
static __device__ __forceinline__ float tanhf_(float x){
  x = fminf(15.f, fmaxf(-15.f, x));
  float e = __expf(-2.f*x);
  return (1.f - e)/(1.f + e);
}

// ---------- prep kernels ----------
// bf16 quad pack (encoder weights, unchanged layout from round 1)
static __device__ __forceinline__ u16 f2bf(float f){
  union{float f; u32 i;} v; v.f = f;
  u32 r = v.i + 0x7fffu + ((v.i >> 16) & 1u);
  return (u16)(r >> 16);
}
__global__ void k_prep(u16* __restrict__ dst, const float* __restrict__ src,
                       int K, int C, int sk, int sc)
{
  int idx = blockIdx.x*256 + threadIdx.x;
  if (idx >= K*C) return;
  int k = idx / C, c = idx - k*C;
  dst[(size_t)(k>>2)*(4*C) + 4*c + (k&3)] = f2bf(src[(size_t)k*sk + (size_t)c*sc]);
}

// f16 B-operand pack: dst[c*Kld + koff + k] = src[k*sk + c*sc], idx over C*K
__global__ void k_pack16(f16* __restrict__ dst, const float* __restrict__ src,
                         int Kld, int koff, int C, int K, int sk, int sc)
{
  int idx = blockIdx.x*256 + threadIdx.x;
  if (idx >= C*K) return;
  int c = idx / K, k = idx - c*K;
  dst[(size_t)c*Kld + koff + k] = (f16)src[(size_t)k*sk + (size_t)c*sc];
}

__global__ void k_zf16(f16* __restrict__ dst, int n)
{
  int idx = blockIdx.x*256 + threadIdx.x;
  if (idx < n) dst[idx] = (f16)0.f;
}

// ---------- Bi-LSTM encoder (round-1 structure; enc now f16 stride 224) ----------
__global__ __launch_bounds__(512) void k_encoder(
    const int* __restrict__ sentences, const float* __restrict__ src_emb,
    const float* __restrict__ b_f, const float* __restrict__ b_b,
    const uint2* __restrict__ wihF, const uint2* __restrict__ whhF,
    const uint2* __restrict__ wihB, const uint2* __restrict__ whhB,
    f16* __restrict__ enc,                 // [B][S][ENC_LD] f16
    float* __restrict__ hTf, float* __restrict__ cTf,
    float* __restrict__ hTb, float* __restrict__ cTb)
{
  const int tid = threadIdx.x;
  const int dir = blockIdx.x >> 7;
  const int bg  = blockIdx.x & 127;
  const int b0  = bg * 8;

  __shared__ alignas(16) float xs[8][E_DIM];
  __shared__ alignas(16) float hs[8][HH];
  __shared__ alignas(16) float zs[8][G4HH];

  const uint2* wih = dir ? wihB : wihF;
  const uint2* whh = dir ? whhB : whhF;
  const float* bias = dir ? b_b : b_f;

  for (int idx = tid; idx < 8*HH; idx += 512) ((float*)hs)[idx] = 0.f;
  float c0r = 0.f, c1r = 0.f;

  const int col = tid;
  const bool act = (col < G4HH);
  const float bias0 = act ? bias[col] : 0.f;

  __syncthreads();

  for (int step = 0; step < S_LEN; ++step) {
    const int s = dir ? (S_LEN-1-step) : step;
    {
      int r = tid >> 6, e = tid & 63;
      int tok = sentences[s*B_N + (b0 + r)];
      xs[r][e] = src_emb[(size_t)tok*E_DIM + e];
    }
    __syncthreads();

    if (act) {
      float acc[8];
      #pragma unroll
      for (int r = 0; r < 8; ++r) acc[r] = bias0;
      #pragma unroll 2
      for (int k4 = 0; k4 < E_DIM/4; ++k4) {
        uint2 u = wih[k4*G4HH + col];
        float w0 = lo_bf(u.x), w1 = hi_bf(u.x), w2 = lo_bf(u.y), w3 = hi_bf(u.y);
        #pragma unroll
        for (int r = 0; r < 8; ++r) {
          float4 xv = *(const float4*)&xs[r][4*k4];
          acc[r] += xv.x*w0 + xv.y*w1 + xv.z*w2 + xv.w*w3;
        }
      }
      #pragma unroll 2
      for (int k4 = 0; k4 < HH/4; ++k4) {
        uint2 u = whh[k4*G4HH + col];
        float w0 = lo_bf(u.x), w1 = hi_bf(u.x), w2 = lo_bf(u.y), w3 = hi_bf(u.y);
        #pragma unroll
        for (int r = 0; r < 8; ++r) {
          float4 hv = *(const float4*)&hs[r][4*k4];
          acc[r] += hv.x*w0 + hv.y*w1 + hv.z*w2 + hv.w*w3;
        }
      }
      #pragma unroll
      for (int r = 0; r < 8; ++r) zs[r][col] = acc[r];
    }
    __syncthreads();

    {
      int r = tid / HH, j = tid - r*HH;
      float c = sigf(zs[r][HH+j])*c0r + sigf(zs[r][j])*tanhf_(zs[r][2*HH+j]);
      float h = sigf(zs[r][3*HH+j])*tanhf_(c);
      c0r = c;
      hs[r][j] = h;
      enc[((size_t)(b0+r)*S_LEN + s)*ENC_LD + dir*HH + j] = (f16)h;
      if (tid < 8*HH - 512) {
        int idx2 = tid + 512;
        int r2 = idx2 / HH, j2 = idx2 - r2*HH;
        float c2 = sigf(zs[r2][HH+j2])*c1r + sigf(zs[r2][j2])*tanhf_(zs[r2][2*HH+j2]);
        float h2 = sigf(zs[r2][3*HH+j2])*tanhf_(c2);
        c1r = c2;
        hs[r2][j2] = h2;
        enc[((size_t)(b0+r2)*S_LEN + s)*ENC_LD + dir*HH + j2] = (f16)h2;
      }
    }
    __syncthreads();
  }

  float* hT = dir ? hTb : hTf;
  float* cT = dir ? cTb : cTf;
  {
    int r = tid / HH, j = tid - r*HH;
    hT[(b0+r)*HH + j] = hs[r][j];
    cT[(b0+r)*HH + j] = c0r;
    if (tid < 8*HH - 512) {
      int idx2 = tid + 512; int r2 = idx2 / HH, j2 = idx2 - r2*HH;
      hT[(b0+r2)*HH + j2] = hs[r2][j2];
      cT[(b0+r2)*HH + j2] = c1r;
    }
  }
}

// ---------- Decoder: 8 batch rows/block, 128 blocks, MFMA f16 ----------
__global__ __launch_bounds__(512, 2) void k_decoder(
  const int* __restrict__ is_prod, const int* __restrict__ prod_ids,
  const int* __restrict__ prim_ids, const int* __restrict__ field_ids,
  const int* __restrict__ parent_t,
  const float* __restrict__ actprod_emb, const float* __restrict__ prim_emb,
  const float* __restrict__ field_emb, const float* __restrict__ b_d,
  const f16* __restrict__ wall,    // [800][640] k-contiguous per gate col
  const f16* __restrict__ wattn,   // [208][224]
  const f16* __restrict__ wav,     // [208][416]
  const f16* __restrict__ enc,     // [B][S][224]
  const float* __restrict__ hTf, const float* __restrict__ cTf,
  const float* __restrict__ hTb, const float* __restrict__ cTb,
  f16* __restrict__ Hbuf, float* __restrict__ out)
{
  const int tid  = threadIdx.x;
  const int lane = tid & 63;
  const int wid  = tid >> 6;          // 8 waves
  const int b0   = blockIdx.x * 8;
  const int arow = lane & 15;
  const int aoff = (lane >> 4) * 8;   // k-octet offset within 32-k tile

  __shared__ alignas(16) f16   xa[8][KTOT];     // [a32 | s_att200 | nft8 | parent200 | h200]
  __shared__ alignas(16) f16   hg[8][KH_PAD];   // h padded for g-MFMA A
  __shared__ alignas(16) f16   gA[8][KH_PAD];   // g (scores operand)
  __shared__ alignas(16) f16   cat[8][KC_PAD];  // [ctx200 | h200 | pad16]
  __shared__ alignas(16) float zs[8][G4H];
  __shared__ alignas(16) float aw[8][S_LEN];
  __shared__ alignas(16) float ctxp[2][8][H_DIM];
  __shared__ float biasd[G4H];

  // ---- init
  for (int idx = tid; idx < G4H; idx += 512) biasd[idx] = b_d[idx];
  for (int idx = tid; idx < 8*24; idx += 512) {        // hg pad [200,224)
    int r = idx / 24; hg[r][200 + idx%24] = (f16)0.f;
  }
  for (int idx = tid; idx < 8*16; idx += 512) {        // cat pad [400,416)
    int r = idx / 16; cat[r][400 + idx%16] = (f16)0.f;
  }
  for (int idx = tid; idx < 8*ATT_D; idx += 512) {     // s_att region zero
    int r = idx / ATT_D; xa[r][ACT_D + idx%ATT_D] = (f16)0.f;
  }
  // h0 / c0 per torch h0.view(-1,H) quirk
  for (int idx = tid; idx < 8*H_DIM; idx += 512) {
    int r = idx / H_DIM, j = idx - r*H_DIM; int b = b0 + r;
    float v;
    if (b < 512) v = (j < HH) ? hTf[(2*b)*HH + j] : hTf[(2*b+1)*HH + (j-HH)];
    else { int bb = b-512; v = (j < HH) ? hTb[(2*bb)*HH + j] : hTb[(2*bb+1)*HH + (j-HH)]; }
    f16 hv = (f16)v;
    xa[r][DEC_IN + j] = hv; hg[r][j] = hv; cat[r][H_DIM + j] = hv;
  }
  float cst[4];
  #pragma unroll
  for (int kk = 0; kk < 4; ++kk) {
    int slot = tid + 512*kk;
    float v = 0.f;
    if (slot < 8*H_DIM) {
      int r = slot / H_DIM, j = slot - r*H_DIM; int b = b0 + r;
      if (b < 512) v = (j < HH) ? cTf[(2*b)*HH + j] : cTf[(2*b+1)*HH + (j-HH)];
      else { int bb = b-512; v = (j < HH) ? cTb[(2*bb)*HH + j] : cTb[(2*bb+1)*HH + (j-HH)]; }
    }
    cst[kk] = v;
  }
  __syncthreads();

  for (int t = 0; t < T_LEN; ++t) {
    // ---- stage a/nft/parent into xa (s_att + h persist). t==0 -> zeros.
    for (int idx = tid; idx < 8*DEC_IN; idx += 512) {
      int r = idx / DEC_IN, k = idx - r*DEC_IN;
      if (k >= ACT_D && k < ACT_D + ATT_D) continue;
      f16 v = (f16)0.f;
      if (t > 0) {
        int b = b0 + r;
        if (k < ACT_D) {
          float f = (is_prod[t*B_N + b] == 1)
            ? actprod_emb[prod_ids[t*B_N + b]*ACT_D + k]
            : prim_emb[prim_ids[t*B_N + b]*ACT_D + k];
          v = (f16)f;
        } else if (k < ACT_D + ATT_D + FLD_D) {
          v = (f16)field_emb[field_ids[t*B_N + b]*FLD_D + (k - ACT_D - ATT_D)];
        } else {
          int pt = parent_t[t*B_N + b];
          v = Hbuf[((size_t)pt*B_N + b)*H_DIM + (k - (ACT_D+ATT_D+FLD_D))];
        }
      }
      xa[r][k] = v;
    }
    __syncthreads();

    // ---- z = [inp|h] @ wall + b_d via MFMA (K=640, 20 k-tiles, 50 n-tiles)
    {
      f16x8 afr[20];
      #pragma unroll
      for (int kk = 0; kk < 20; ++kk) {
        f16x8 v = {0,0,0,0,0,0,0,0};
        if (arow < 8) v = *(const f16x8*)&xa[arow][kk*32 + aoff];
        afr[kk] = v;
      }
      int t_begin = wid*6 + (wid < 2 ? wid : 2);
      int t_count = 6 + (wid < 2 ? 1 : 0);
      for (int ti = 0; ti < t_count; ti += 2) {
        int ta = t_begin + ti;
        bool hasb = (ti + 1 < t_count);
        int tb = hasb ? ta + 1 : ta;
        int ca = ta*16 + (lane & 15);
        int cb = tb*16 + (lane & 15);
        float bva = biasd[ca], bvb = biasd[cb];
        f32x4 acca = {bva, bva, bva, bva};
        f32x4 accb = {bvb, bvb, bvb, bvb};
        const f16* pa = wall + (size_t)ca*KTOT + aoff;
        const f16* pb = wall + (size_t)cb*KTOT + aoff;
        #pragma unroll
        for (int kk = 0; kk < 20; ++kk) {
          f16x8 Ba = *(const f16x8*)(pa + kk*32);
          f16x8 Bb = *(const f16x8*)(pb + kk*32);
          acca = MFMA16(afr[kk], Ba, acca);
          accb = MFMA16(afr[kk], Bb, accb);
        }
        if (lane < 32) {
          int rb = (lane >> 4) * 4;
          #pragma unroll
          for (int i2 = 0; i2 < 4; ++i2) zs[rb+i2][ca] = acca[i2];
          if (hasb) {
            #pragma unroll
            for (int i2 = 0; i2 < 4; ++i2) zs[rb+i2][cb] = accb[i2];
          }
        }
      }
    }
    __syncthreads();

    // ---- LSTM cell (i,f,g,o)
    #pragma unroll
    for (int kk = 0; kk < 4; ++kk) {
      int slot = tid + 512*kk;
      if (slot < 8*H_DIM) {
        int r = slot / H_DIM, j = slot - r*H_DIM;
        float c = sigf(zs[r][H_DIM+j])*cst[kk] + sigf(zs[r][j])*tanhf_(zs[r][2*H_DIM+j]);
        float h = sigf(zs[r][3*H_DIM+j])*tanhf_(c);
        cst[kk] = c;
        f16 hv = (f16)h;
        xa[r][DEC_IN + j] = hv; hg[r][j] = hv; cat[r][H_DIM + j] = hv;
        Hbuf[((size_t)t*B_N + (b0+r))*H_DIM + j] = hv;
      }
    }
    __syncthreads();

    // ---- g = W_attn^T h via MFMA (K=224, 7 k-tiles, 13 n-tiles)
    {
      f16x8 ga[7];
      #pragma unroll
      for (int kk = 0; kk < 7; ++kk) {
        f16x8 v = {0,0,0,0,0,0,0,0};
        if (arow < 8) v = *(const f16x8*)&hg[arow][kk*32 + aoff];
        ga[kk] = v;
      }
      #pragma unroll
      for (int pass = 0; pass < 2; ++pass) {
        int tt = wid + pass*8;
        if (tt < 13) {
          int c = tt*16 + (lane & 15);
          f32x4 acc = {0.f,0.f,0.f,0.f};
          const f16* p = wattn + (size_t)c*KH_PAD + aoff;
          #pragma unroll
          for (int kk = 0; kk < 7; ++kk)
            acc = MFMA16(ga[kk], *(const f16x8*)(p + kk*32), acc);
          if (lane < 32) {
            int rb = (lane >> 4) * 4;
            #pragma unroll
            for (int i2 = 0; i2 < 4; ++i2)
              if (c < H_DIM) gA[rb+i2][c] = (f16)acc[i2];
          }
        }
      }
    }
    __syncthreads();

    // ---- scores + softmax: wave `wid` owns row r=wid; lanes own s and s+64
    {
      int r = wid;
      const f16* gp = &gA[r][0];
      const f16* ep0 = enc + ((size_t)(b0+r)*S_LEN + lane)*ENC_LD;
      const f16* ep1 = ep0 + (size_t)64*ENC_LD;
      float s0v = 0.f, s1v = 0.f;
      #pragma unroll 5
      for (int o = 0; o < 25; ++o) {
        f16x8 g8 = *(const f16x8*)(gp + 8*o);
        f16x8 e0 = *(const f16x8*)(ep0 + 8*o);
        f16x8 e1 = *(const f16x8*)(ep1 + 8*o);
        #pragma unroll
        for (int i = 0; i < 8; ++i) {
          s0v += (float)e0[i] * (float)g8[i];
          s1v += (float)e1[i] * (float)g8[i];
        }
      }
      float m = fmaxf(s0v, s1v);
      #pragma unroll
      for (int d = 32; d; d >>= 1) m = fmaxf(m, __shfl_xor(m, d));
      float e0v = __expf(s0v - m), e1v = __expf(s1v - m);
      float sm = e0v + e1v;
      #pragma unroll
      for (int d = 32; d; d >>= 1) sm += __shfl_xor(sm, d);
      float rd = 1.f / sm;
      aw[r][lane]      = e0v * rd;
      aw[r][lane + 64] = e1v * rd;
    }
    __syncthreads();

    // ---- ctx partials: (r, col-octet o<25, s-half q) = 400 threads
    if (tid < 400) {
      int q = tid & 1, o = (tid >> 1) % 25, r = tid / 50;
      const f16* ep = enc + ((size_t)(b0+r)*S_LEN + q*64)*ENC_LD + 8*o;
      float acc[8] = {0.f,0.f,0.f,0.f,0.f,0.f,0.f,0.f};
      #pragma unroll 4
      for (int s2 = 0; s2 < 64; ++s2) {
        float w = aw[r][q*64 + s2];
        f16x8 e8 = *(const f16x8*)(ep + (size_t)s2*ENC_LD);
        #pragma unroll
        for (int i = 0; i < 8; ++i) acc[i] += w * (float)e8[i];
      }
      #pragma unroll
      for (int i = 0; i < 8; ++i) ctxp[q][r][8*o + i] = acc[i];
    }
    __syncthreads();

    // ---- combine ctx halves -> cat (f16)
    #pragma unroll
    for (int kk = 0; kk < 4; ++kk) {
      int slot = tid + 512*kk;
      if (slot < 8*H_DIM) {
        int r = slot / H_DIM, cc = slot - r*H_DIM;
        cat[r][cc] = (f16)(ctxp[0][r][cc] + ctxp[1][r][cc]);
      }
    }
    __syncthreads();

    // ---- s_att = tanh([ctx|h] @ wav) via MFMA (K=416, 13 k-tiles, 13 n-tiles)
    {
      f16x8 sa[13];
      #pragma unroll
      for (int kk = 0; kk < 13; ++kk) {
        f16x8 v = {0,0,0,0,0,0,0,0};
        if (arow < 8) v = *(const f16x8*)&cat[arow][kk*32 + aoff];
        sa[kk] = v;
      }
      #pragma unroll
      for (int pass = 0; pass < 2; ++pass) {
        int tt = wid + pass*8;
        if (tt < 13) {
          int c = tt*16 + (lane & 15);
          f32x4 acc = {0.f,0.f,0.f,0.f};
          const f16* p = wav + (size_t)c*KC_PAD + aoff;
          #pragma unroll
          for (int kk = 0; kk < 13; ++kk)
            acc = MFMA16(sa[kk], *(const f16x8*)(p + kk*32), acc);
          if (lane < 32 && c < ATT_D) {
            int rb = (lane >> 4) * 4;
            #pragma unroll
            for (int i2 = 0; i2 < 4; ++i2) {
              float v = tanhf_(acc[i2]);
              out[((size_t)t*B_N + (b0+rb+i2))*ATT_D + c] = v;
              xa[rb+i2][ACT_D + c] = (f16)v;
            }
          }
        }
      }
    }
    __syncthreads();
  }
}

extern "C" void kernel_launch(void* const* d_in, const int* in_sizes, int n_in,
                              void* d_out, int out_size, void* d_ws, size_t ws_size,
                              hipStream_t stream)
{
  const int*   sentences = (const int*)  d_in[0];
  const int*   is_prod   = (const int*)  d_in[1];
  const int*   prod_ids  = (const int*)  d_in[2];
  const int*   prim_ids  = (const int*)  d_in[3];
  const int*   field_ids = (const int*)  d_in[4];
  const int*   parent_t  = (const int*)  d_in[5];
  const float* src_emb   = (const float*)d_in[6];
  const float* actprod   = (const float*)d_in[7];
  const float* prim_emb  = (const float*)d_in[8];
  const float* field_emb = (const float*)d_in[9];
  const float* Wih_f = (const float*)d_in[10];
  const float* Whh_f = (const float*)d_in[11];
  const float* b_f   = (const float*)d_in[12];
  const float* Wih_b = (const float*)d_in[13];
  const float* Whh_b = (const float*)d_in[14];
  const float* b_b   = (const float*)d_in[15];
  const float* Wih_d = (const float*)d_in[16];
  const float* Whh_d = (const float*)d_in[17];
  const float* b_d   = (const float*)d_in[18];
  const float* W_attn= (const float*)d_in[19];
  const float* W_av  = (const float*)d_in[20];
  (void)in_sizes; (void)n_in; (void)out_size; (void)ws_size;

  char* ws = (char*)d_ws;
  size_t off = 0;
  auto take = [&](size_t bytes) -> void* {
    void* p = ws + off;
    off = (off + bytes + 255) & ~(size_t)255;
    return p;
  };
  u16* wihF = (u16*)take((size_t)64*400*2);
  u16* whhF = (u16*)take((size_t)100*400*2);
  u16* wihB = (u16*)take((size_t)64*400*2);
  u16* whhB = (u16*)take((size_t)100*400*2);
  f16* wall16  = (f16*)take((size_t)800*640*2);
  f16* wattn16 = (f16*)take((size_t)NCOL_PAD*KH_PAD*2);
  f16* wav16   = (f16*)take((size_t)NCOL_PAD*KC_PAD*2);
  f16* enc16   = (f16*)take((size_t)B_N*S_LEN*ENC_LD*2);
  float* hTf = (float*)take((size_t)B_N*HH*4);
  float* cTf = (float*)take((size_t)B_N*HH*4);
  float* hTb = (float*)take((size_t)B_N*HH*4);
  float* cTb = (float*)take((size_t)B_N*HH*4);
  f16* Hbuf16 = (f16*)take((size_t)T_LEN*B_N*H_DIM*2);
  float* outp = (float*)d_out;

  auto prep = [&](u16* dst, const float* src, int K, int C, int sk, int sc){
    int n = K*C;
    k_prep<<<(n+255)/256, 256, 0, stream>>>(dst, src, K, C, sk, sc);
  };
  prep(wihF, Wih_f, 64, 400, 1, 64);
  prep(whhF, Whh_f, 100, 400, 1, 100);
  prep(wihB, Wih_b, 64, 400, 1, 64);
  prep(whhB, Whh_b, 100, 400, 1, 100);

  // decoder f16 weight packs
  {
    int n;
    n = NCOL_PAD*KH_PAD; k_zf16<<<(n+255)/256,256,0,stream>>>(wattn16, n);
    n = NCOL_PAD*KC_PAD; k_zf16<<<(n+255)/256,256,0,stream>>>(wav16, n);
    // wall: [800][640]; k<440 from Wih_d (row-major [800][440]), k>=440 from Whh_d [800][200]
    n = 800*440; k_pack16<<<(n+255)/256,256,0,stream>>>(wall16, Wih_d, KTOT, 0,   800, 440, 1, 440);
    n = 800*200; k_pack16<<<(n+255)/256,256,0,stream>>>(wall16, Whh_d, KTOT, 440, 800, 200, 1, 200);
    // wattn: B[k][n] = W_attn[k][n]  (g = W_attn^T h)
    n = 200*200; k_pack16<<<(n+255)/256,256,0,stream>>>(wattn16, W_attn, KH_PAD, 0, 200, 200, 200, 1);
    // wav: B[k][n] = W_av[n][k]
    n = 200*400; k_pack16<<<(n+255)/256,256,0,stream>>>(wav16, W_av, KC_PAD, 0, 200, 400, 1, 400);
  }

  // zero enc (pad columns must be 0; buffer is re-poisoned before every launch)
  hipMemsetAsync(enc16, 0, (size_t)B_N*S_LEN*ENC_LD*2, stream);

  k_encoder<<<256, 512, 0, stream>>>(sentences, src_emb, b_f, b_b,
      (const uint2*)wihF, (const uint2*)whhF, (const uint2*)wihB, (const uint2*)whhB,
      enc16, hTf, cTf, hTb, cTb);

  k_decoder<<<128, 512, 0, stream>>>(is_prod, prod_ids, prim_ids, field_ids, parent_t,
      actprod, prim_emb, field_emb, b_d,
      wall16, wattn16, wav16,
      enc16, hTf, cTf, hTb, cTb, Hbuf16, outp);
}

// Round 3
// 7847.195 us; speedup vs baseline: 1.4050x; 1.0195x over previous
//
#include <hip/hip_runtime.h>

#define S_LEN 128
#define B_N   1024
#define T_LEN 96
#define E_DIM 64
#define HH    100
#define H_DIM 200
#define ACT_D 32
#define FLD_D 8
#define ATT_D 200
#define DEC_IN 440          // 32 + 200 + 8 + 200
#define KTOT  640           // DEC_IN + H_DIM
#define G4H   800           // 4*H
#define G4HH  400           // 4*HH
#define KH_PAD 224          // wattn k-pad (7*32)
#define KC_PAD 416          // wav k-pad (13*32)
#define NCOL_PAD 208        // 13*16 col pad
#define EK_ROWS 208         // enc_ks k rows (13*16)
// LDS strides (f16 elems) chosen for 16B alignment + distinct banks across 8 rows
#define XA_LD 648
#define HG_LD 232
#define GA_LD 232
#define CAT_LD 424

typedef unsigned int  u32;
typedef unsigned short u16;
typedef _Float16 f16;
typedef _Float16 f16x8 __attribute__((ext_vector_type(8)));
typedef _Float16 f16x4 __attribute__((ext_vector_type(4)));
typedef float    f32x4 __attribute__((ext_vector_type(4)));

#define MFMA16(a,b,c) __builtin_amdgcn_mfma_f32_16x16x32_f16((a),(b),(c),0,0,0)

static __device__ __forceinline__ float lo_bf(u32 u){ union{u32 i; float f;}v; v.i = u<<16; return v.f; }
static __device__ __forceinline__ float hi_bf(u32 u){ union{u32 i; float f;}v; v.i = u & 0xffff0000u; return v.f; }
static __device__ __forceinline__ float sigf(float x){
  x = fminf(30.f, fmaxf(-30.f, x));
  return 1.f/(1.f + __expf(-x));
}
static __device__ __forceinline__ float tanhf_(float x){
  x = fminf(15.f, fmaxf(-15.f, x));
  float e = __expf(-2.f*x);
  return (1.f - e)/(1.f + e);
}

// ---------- prep kernels ----------
static __device__ __forceinline__ u16 f2bf(float f){
  union{float f; u32 i;} v; v.f = f;
  u32 r = v.i + 0x7fffu + ((v.i >> 16) & 1u);
  return (u16)(r >> 16);
}
__global__ void k_prep(u16* __restrict__ dst, const float* __restrict__ src,
                       int K, int C, int sk, int sc)
{
  int idx = blockIdx.x*256 + threadIdx.x;
  if (idx >= K*C) return;
  int k = idx / C, c = idx - k*C;
  dst[(size_t)(k>>2)*(4*C) + 4*c + (k&3)] = f2bf(src[(size_t)k*sk + (size_t)c*sc]);
}

__global__ void k_pack16(f16* __restrict__ dst, const float* __restrict__ src,
                         int Kld, int koff, int C, int K, int sk, int sc)
{
  int idx = blockIdx.x*256 + threadIdx.x;
  if (idx >= C*K) return;
  int c = idx / K, k = idx - c*K;
  dst[(size_t)c*Kld + koff + k] = (f16)src[(size_t)k*sk + (size_t)c*sc];
}

__global__ void k_zf16(f16* __restrict__ dst, int n)
{
  int idx = blockIdx.x*256 + threadIdx.x;
  if (idx < n) dst[idx] = (f16)0.f;
}

// Transpose enc_sk[b][s][200] -> enc_ks[b][k][128]; one block per b.
__global__ __launch_bounds__(256) void k_transpose(
    const f16* __restrict__ enc_sk, f16* __restrict__ enc_ks)
{
  __shared__ f16 ld[H_DIM][136];
  const int b = blockIdx.x, tid = threadIdx.x;
  const f16* src = enc_sk + (size_t)b*S_LEN*H_DIM;
  // phase 1: coalesced read, scatter into LDS as [k][s]
  for (int idx = tid; idx < S_LEN*(H_DIM/4); idx += 256) {
    int s = idx / (H_DIM/4), jc = idx - s*(H_DIM/4);
    f16x4 v = *(const f16x4*)(src + (size_t)s*H_DIM + 4*jc);
    #pragma unroll
    for (int i = 0; i < 4; ++i) ld[4*jc + i][s] = v[i];
  }
  __syncthreads();
  // phase 2: read LDS rows contiguous, coalesced 16B global stores
  f16* dst = enc_ks + (size_t)b*EK_ROWS*S_LEN;
  for (int idx = tid; idx < H_DIM*(S_LEN/8); idx += 256) {
    int k = idx / (S_LEN/8), so = idx - k*(S_LEN/8);
    f16x8 v;
    #pragma unroll
    for (int i = 0; i < 8; ++i) v[i] = ld[k][8*so + i];
    *(f16x8*)(dst + (size_t)k*S_LEN + 8*so) = v;
  }
}

// ---------- Bi-LSTM encoder ----------
__global__ __launch_bounds__(512) void k_encoder(
    const int* __restrict__ sentences, const float* __restrict__ src_emb,
    const float* __restrict__ b_f, const float* __restrict__ b_b,
    const uint2* __restrict__ wihF, const uint2* __restrict__ whhF,
    const uint2* __restrict__ wihB, const uint2* __restrict__ whhB,
    f16* __restrict__ enc_sk,              // [B][S][200] f16
    float* __restrict__ hTf, float* __restrict__ cTf,
    float* __restrict__ hTb, float* __restrict__ cTb)
{
  const int tid = threadIdx.x;
  const int dir = blockIdx.x >> 7;
  const int bg  = blockIdx.x & 127;
  const int b0  = bg * 8;

  __shared__ alignas(16) float xs[8][E_DIM];
  __shared__ alignas(16) float hs[8][HH];
  __shared__ alignas(16) float zs[8][G4HH];

  const uint2* wih = dir ? wihB : wihF;
  const uint2* whh = dir ? whhB : whhF;
  const float* bias = dir ? b_b : b_f;

  for (int idx = tid; idx < 8*HH; idx += 512) ((float*)hs)[idx] = 0.f;
  float c0r = 0.f, c1r = 0.f;

  const int col = tid;
  const bool act = (col < G4HH);
  const float bias0 = act ? bias[col] : 0.f;

  __syncthreads();

  for (int step = 0; step < S_LEN; ++step) {
    const int s = dir ? (S_LEN-1-step) : step;
    {
      int r = tid >> 6, e = tid & 63;
      int tok = sentences[s*B_N + (b0 + r)];
      xs[r][e] = src_emb[(size_t)tok*E_DIM + e];
    }
    __syncthreads();

    if (act) {
      float acc[8];
      #pragma unroll
      for (int r = 0; r < 8; ++r) acc[r] = bias0;
      #pragma unroll 2
      for (int k4 = 0; k4 < E_DIM/4; ++k4) {
        uint2 u = wih[k4*G4HH + col];
        float w0 = lo_bf(u.x), w1 = hi_bf(u.x), w2 = lo_bf(u.y), w3 = hi_bf(u.y);
        #pragma unroll
        for (int r = 0; r < 8; ++r) {
          float4 xv = *(const float4*)&xs[r][4*k4];
          acc[r] += xv.x*w0 + xv.y*w1 + xv.z*w2 + xv.w*w3;
        }
      }
      #pragma unroll 2
      for (int k4 = 0; k4 < HH/4; ++k4) {
        uint2 u = whh[k4*G4HH + col];
        float w0 = lo_bf(u.x), w1 = hi_bf(u.x), w2 = lo_bf(u.y), w3 = hi_bf(u.y);
        #pragma unroll
        for (int r = 0; r < 8; ++r) {
          float4 hv = *(const float4*)&hs[r][4*k4];
          acc[r] += hv.x*w0 + hv.y*w1 + hv.z*w2 + hv.w*w3;
        }
      }
      #pragma unroll
      for (int r = 0; r < 8; ++r) zs[r][col] = acc[r];
    }
    __syncthreads();

    {
      int r = tid / HH, j = tid - r*HH;
      float c = sigf(zs[r][HH+j])*c0r + sigf(zs[r][j])*tanhf_(zs[r][2*HH+j]);
      float h = sigf(zs[r][3*HH+j])*tanhf_(c);
      c0r = c;
      hs[r][j] = h;
      enc_sk[((size_t)(b0+r)*S_LEN + s)*H_DIM + dir*HH + j] = (f16)h;
      if (tid < 8*HH - 512) {
        int idx2 = tid + 512;
        int r2 = idx2 / HH, j2 = idx2 - r2*HH;
        float c2 = sigf(zs[r2][HH+j2])*c1r + sigf(zs[r2][j2])*tanhf_(zs[r2][2*HH+j2]);
        float h2 = sigf(zs[r2][3*HH+j2])*tanhf_(c2);
        c1r = c2;
        hs[r2][j2] = h2;
        enc_sk[((size_t)(b0+r2)*S_LEN + s)*H_DIM + dir*HH + j2] = (f16)h2;
      }
    }
    __syncthreads();
  }

  float* hT = dir ? hTb : hTf;
  float* cT = dir ? cTb : cTf;
  {
    int r = tid / HH, j = tid - r*HH;
    hT[(b0+r)*HH + j] = hs[r][j];
    cT[(b0+r)*HH + j] = c0r;
    if (tid < 8*HH - 512) {
      int idx2 = tid + 512; int r2 = idx2 / HH, j2 = idx2 - r2*HH;
      hT[(b0+r2)*HH + j2] = hs[r2][j2];
      cT[(b0+r2)*HH + j2] = c1r;
    }
  }
}

// ---------- Decoder: 8 rows/block, 128 blocks, MFMA + coalesced enc_ks ----------
__global__ __launch_bounds__(512, 2) void k_decoder(
  const int* __restrict__ is_prod, const int* __restrict__ prod_ids,
  const int* __restrict__ prim_ids, const int* __restrict__ field_ids,
  const int* __restrict__ parent_t,
  const float* __restrict__ actprod_emb, const float* __restrict__ prim_emb,
  const float* __restrict__ field_emb, const float* __restrict__ b_d,
  const f16* __restrict__ wall,    // [800][640]
  const f16* __restrict__ wattn,   // [208][224]
  const f16* __restrict__ wav,     // [208][416]
  const f16* __restrict__ enc_ks,  // [B][208][128]
  const float* __restrict__ hTf, const float* __restrict__ cTf,
  const float* __restrict__ hTb, const float* __restrict__ cTb,
  f16* __restrict__ Hbuf, float* __restrict__ out)
{
  const int tid  = threadIdx.x;
  const int lane = tid & 63;
  const int wid  = tid >> 6;          // 8 waves
  const int b0   = blockIdx.x * 8;
  const int arow = lane & 15;
  const int aoff = (lane >> 4) * 8;

  __shared__ alignas(16) f16   xa[8][XA_LD];    // [a32|s_att200|nft8|parent200|h200]
  __shared__ alignas(16) f16   hg[8][HG_LD];    // h (k-padded to 224)
  __shared__ alignas(16) f16   gA[8][GA_LD];    // g
  __shared__ alignas(16) f16   cat[8][CAT_LD];  // [ctx200|h200|pad16]
  __shared__ alignas(16) f16   aw_sh[8][S_LEN]; // softmax weights
  __shared__ alignas(16) float zs[8][G4H];
  __shared__ float biasd[G4H];

  // ---- init
  for (int idx = tid; idx < G4H; idx += 512) biasd[idx] = b_d[idx];
  for (int idx = tid; idx < 8*(HG_LD-H_DIM); idx += 512) {
    int n = HG_LD-H_DIM; hg[idx/n][H_DIM + idx%n] = (f16)0.f;
  }
  for (int idx = tid; idx < 8*(GA_LD-H_DIM); idx += 512) {
    int n = GA_LD-H_DIM; gA[idx/n][H_DIM + idx%n] = (f16)0.f;
  }
  for (int idx = tid; idx < 8*(CAT_LD-2*H_DIM); idx += 512) {
    int n = CAT_LD-2*H_DIM; cat[idx/n][2*H_DIM + idx%n] = (f16)0.f;
  }
  for (int idx = tid; idx < 8*ATT_D; idx += 512) {
    xa[idx/ATT_D][ACT_D + idx%ATT_D] = (f16)0.f;
  }
  for (int idx = tid; idx < 8*H_DIM; idx += 512) {
    int r = idx / H_DIM, j = idx - r*H_DIM; int b = b0 + r;
    float v;
    if (b < 512) v = (j < HH) ? hTf[(2*b)*HH + j] : hTf[(2*b+1)*HH + (j-HH)];
    else { int bb = b-512; v = (j < HH) ? hTb[(2*bb)*HH + j] : hTb[(2*bb+1)*HH + (j-HH)]; }
    f16 hv = (f16)v;
    xa[r][DEC_IN + j] = hv; hg[r][j] = hv; cat[r][H_DIM + j] = hv;
  }
  float cst[4];
  #pragma unroll
  for (int kk = 0; kk < 4; ++kk) {
    int slot = tid + 512*kk;
    float v = 0.f;
    if (slot < 8*H_DIM) {
      int r = slot / H_DIM, j = slot - r*H_DIM; int b = b0 + r;
      if (b < 512) v = (j < HH) ? cTf[(2*b)*HH + j] : cTf[(2*b+1)*HH + (j-HH)];
      else { int bb = b-512; v = (j < HH) ? cTb[(2*bb)*HH + j] : cTb[(2*bb+1)*HH + (j-HH)]; }
    }
    cst[kk] = v;
  }
  __syncthreads();

  for (int t = 0; t < T_LEN; ++t) {
    // ---- stage a/nft/parent (s_att + h persist). t==0 -> zeros.
    for (int idx = tid; idx < 8*DEC_IN; idx += 512) {
      int r = idx / DEC_IN, k = idx - r*DEC_IN;
      if (k >= ACT_D && k < ACT_D + ATT_D) continue;
      f16 v = (f16)0.f;
      if (t > 0) {
        int b = b0 + r;
        if (k < ACT_D) {
          float f = (is_prod[t*B_N + b] == 1)
            ? actprod_emb[prod_ids[t*B_N + b]*ACT_D + k]
            : prim_emb[prim_ids[t*B_N + b]*ACT_D + k];
          v = (f16)f;
        } else if (k < ACT_D + ATT_D + FLD_D) {
          v = (f16)field_emb[field_ids[t*B_N + b]*FLD_D + (k - ACT_D - ATT_D)];
        } else {
          int pt = parent_t[t*B_N + b];
          v = Hbuf[((size_t)pt*B_N + b)*H_DIM + (k - (ACT_D+ATT_D+FLD_D))];
        }
      }
      xa[r][k] = v;
    }
    __syncthreads();

    // ---- z = [inp|h] @ wall + b_d via MFMA (20 k-tiles, 50 n-tiles)
    {
      f16x8 afr[20];
      #pragma unroll
      for (int kk = 0; kk < 20; ++kk) {
        f16x8 v = {0,0,0,0,0,0,0,0};
        if (arow < 8) v = *(const f16x8*)&xa[arow][kk*32 + aoff];
        afr[kk] = v;
      }
      int t_begin = wid*6 + (wid < 2 ? wid : 2);
      int t_count = 6 + (wid < 2 ? 1 : 0);
      for (int ti = 0; ti < t_count; ti += 2) {
        int ta = t_begin + ti;
        bool hasb = (ti + 1 < t_count);
        int tb = hasb ? ta + 1 : ta;
        int ca = ta*16 + arow;
        int cb = tb*16 + arow;
        float bva = biasd[ca], bvb = biasd[cb];
        f32x4 acca = {bva, bva, bva, bva};
        f32x4 accb = {bvb, bvb, bvb, bvb};
        const f16* pa = wall + (size_t)ca*KTOT + aoff;
        const f16* pb = wall + (size_t)cb*KTOT + aoff;
        #pragma unroll
        for (int kk = 0; kk < 20; ++kk) {
          f16x8 Ba = *(const f16x8*)(pa + kk*32);
          f16x8 Bb = *(const f16x8*)(pb + kk*32);
          acca = MFMA16(afr[kk], Ba, acca);
          accb = MFMA16(afr[kk], Bb, accb);
        }
        if (lane < 32) {
          int rb = (lane >> 4) * 4;
          #pragma unroll
          for (int i2 = 0; i2 < 4; ++i2) zs[rb+i2][ca] = acca[i2];
          if (hasb) {
            #pragma unroll
            for (int i2 = 0; i2 < 4; ++i2) zs[rb+i2][cb] = accb[i2];
          }
        }
      }
    }
    __syncthreads();

    // ---- LSTM cell (i,f,g,o)
    #pragma unroll
    for (int kk = 0; kk < 4; ++kk) {
      int slot = tid + 512*kk;
      if (slot < 8*H_DIM) {
        int r = slot / H_DIM, j = slot - r*H_DIM;
        float c = sigf(zs[r][H_DIM+j])*cst[kk] + sigf(zs[r][j])*tanhf_(zs[r][2*H_DIM+j]);
        float h = sigf(zs[r][3*H_DIM+j])*tanhf_(c);
        cst[kk] = c;
        f16 hv = (f16)h;
        xa[r][DEC_IN + j] = hv; hg[r][j] = hv; cat[r][H_DIM + j] = hv;
        Hbuf[((size_t)t*B_N + (b0+r))*H_DIM + j] = hv;
      }
    }
    __syncthreads();

    // ---- g = W_attn^T h via MFMA (7 k-tiles, 13 n-tiles)
    {
      f16x8 ga[7];
      #pragma unroll
      for (int kk = 0; kk < 7; ++kk) {
        f16x8 v = {0,0,0,0,0,0,0,0};
        if (arow < 8) v = *(const f16x8*)&hg[arow][kk*32 + aoff];
        ga[kk] = v;
      }
      #pragma unroll
      for (int pass = 0; pass < 2; ++pass) {
        int tt = wid + pass*8;
        if (tt < 13) {
          int c = tt*16 + arow;
          f32x4 acc = {0.f,0.f,0.f,0.f};
          const f16* p = wattn + (size_t)c*KH_PAD + aoff;
          #pragma unroll
          for (int kk = 0; kk < 7; ++kk)
            acc = MFMA16(ga[kk], *(const f16x8*)(p + kk*32), acc);
          if (lane < 32) {
            int rb = (lane >> 4) * 4;
            #pragma unroll
            for (int i2 = 0; i2 < 4; ++i2)
              if (c < H_DIM) gA[rb+i2][c] = (f16)acc[i2];
          }
        }
      }
    }
    __syncthreads();

    // ---- scores + softmax: wave owns row r=wid; lanes = 16 s-octets x 4 k-parts
    {
      const int r = wid;
      const int sl = lane & 15, kp = lane >> 4;
      const f16* ep = enc_ks + ((size_t)(b0+r)*EK_ROWS + kp*52)*S_LEN + 8*sl;
      const f16* gp = &gA[r][kp*52];
      float acc[8] = {0.f,0.f,0.f,0.f,0.f,0.f,0.f,0.f};
      #pragma unroll 4
      for (int i = 0; i < 52; ++i) {
        f16x8 e8 = *(const f16x8*)(ep + (size_t)i*S_LEN);
        float gf = (float)gp[i];
        #pragma unroll
        for (int q = 0; q < 8; ++q) acc[q] += gf * (float)e8[q];
      }
      #pragma unroll
      for (int q = 0; q < 8; ++q) {
        acc[q] += __shfl_xor(acc[q], 16);
        acc[q] += __shfl_xor(acc[q], 32);
      }
      float m = acc[0];
      #pragma unroll
      for (int q = 1; q < 8; ++q) m = fmaxf(m, acc[q]);
      #pragma unroll
      for (int d = 1; d < 16; d <<= 1) m = fmaxf(m, __shfl_xor(m, d));
      float e[8], sm = 0.f;
      #pragma unroll
      for (int q = 0; q < 8; ++q) { e[q] = __expf(acc[q] - m); sm += e[q]; }
      #pragma unroll
      for (int d = 1; d < 16; d <<= 1) sm += __shfl_xor(sm, d);
      float rd = 1.f / sm;
      if (kp == 0) {
        f16x8 w;
        #pragma unroll
        for (int q = 0; q < 8; ++q) w[q] = (f16)(e[q] * rd);
        *(f16x8*)&aw_sh[r][8*sl] = w;
      }
    }
    __syncthreads();

    // ---- ctx via block-diagonal MFMA: C[r][k_enc], K'=(r',s)=1024
    {
      #pragma unroll
      for (int pass = 0; pass < 2; ++pass) {
        int tt = wid + pass*8;
        if (tt < 13) {
          int c = tt*16 + arow;
          f32x4 acc = {0.f,0.f,0.f,0.f};
          const f16* eb = enc_ks + (size_t)b0*EK_ROWS*S_LEN + (size_t)c*S_LEN + aoff;
          #pragma unroll 4
          for (int kt = 0; kt < 32; ++kt) {
            int rp = kt >> 2;
            int s0 = (kt & 3) * 32;
            f16x8 a = {0,0,0,0,0,0,0,0};
            if (arow == rp) a = *(const f16x8*)&aw_sh[rp][s0 + aoff];
            f16x8 bf = *(const f16x8*)(eb + (size_t)rp*EK_ROWS*S_LEN + s0);
            acc = MFMA16(a, bf, acc);
          }
          if (lane < 32 && c < H_DIM) {
            int rb = (lane >> 4) * 4;
            #pragma unroll
            for (int i2 = 0; i2 < 4; ++i2) cat[rb+i2][c] = (f16)acc[i2];
          }
        }
      }
    }
    __syncthreads();

    // ---- s_att = tanh([ctx|h] @ wav) via MFMA (13 k-tiles, 13 n-tiles)
    {
      f16x8 sa[13];
      #pragma unroll
      for (int kk = 0; kk < 13; ++kk) {
        f16x8 v = {0,0,0,0,0,0,0,0};
        if (arow < 8) v = *(const f16x8*)&cat[arow][kk*32 + aoff];
        sa[kk] = v;
      }
      #pragma unroll
      for (int pass = 0; pass < 2; ++pass) {
        int tt = wid + pass*8;
        if (tt < 13) {
          int c = tt*16 + arow;
          f32x4 acc = {0.f,0.f,0.f,0.f};
          const f16* p = wav + (size_t)c*KC_PAD + aoff;
          #pragma unroll
          for (int kk = 0; kk < 13; ++kk)
            acc = MFMA16(sa[kk], *(const f16x8*)(p + kk*32), acc);
          if (lane < 32 && c < ATT_D) {
            int rb = (lane >> 4) * 4;
            #pragma unroll
            for (int i2 = 0; i2 < 4; ++i2) {
              float v = tanhf_(acc[i2]);
              out[((size_t)t*B_N + (b0+rb+i2))*ATT_D + c] = v;
              xa[rb+i2][ACT_D + c] = (f16)v;
            }
          }
        }
      }
    }
    __syncthreads();
  }
}

extern "C" void kernel_launch(void* const* d_in, const int* in_sizes, int n_in,
                              void* d_out, int out_size, void* d_ws, size_t ws_size,
                              hipStream_t stream)
{
  const int*   sentences = (const int*)  d_in[0];
  const int*   is_prod   = (const int*)  d_in[1];
  const int*   prod_ids  = (const int*)  d_in[2];
  const int*   prim_ids  = (const int*)  d_in[3];
  const int*   field_ids = (const int*)  d_in[4];
  const int*   parent_t  = (const int*)  d_in[5];
  const float* src_emb   = (const float*)d_in[6];
  const float* actprod   = (const float*)d_in[7];
  const float* prim_emb  = (const float*)d_in[8];
  const float* field_emb = (const float*)d_in[9];
  const float* Wih_f = (const float*)d_in[10];
  const float* Whh_f = (const float*)d_in[11];
  const float* b_f   = (const float*)d_in[12];
  const float* Wih_b = (const float*)d_in[13];
  const float* Whh_b = (const float*)d_in[14];
  const float* b_b   = (const float*)d_in[15];
  const float* Wih_d = (const float*)d_in[16];
  const float* Whh_d = (const float*)d_in[17];
  const float* b_d   = (const float*)d_in[18];
  const float* W_attn= (const float*)d_in[19];
  const float* W_av  = (const float*)d_in[20];
  (void)in_sizes; (void)n_in; (void)out_size; (void)ws_size;

  char* ws = (char*)d_ws;
  size_t off = 0;
  auto take = [&](size_t bytes) -> void* {
    void* p = ws + off;
    off = (off + bytes + 255) & ~(size_t)255;
    return p;
  };
  u16* wihF = (u16*)take((size_t)64*400*2);
  u16* whhF = (u16*)take((size_t)100*400*2);
  u16* wihB = (u16*)take((size_t)64*400*2);
  u16* whhB = (u16*)take((size_t)100*400*2);
  f16* wall16  = (f16*)take((size_t)800*640*2);
  f16* wattn16 = (f16*)take((size_t)NCOL_PAD*KH_PAD*2);
  f16* wav16   = (f16*)take((size_t)NCOL_PAD*KC_PAD*2);
  f16* enc_sk  = (f16*)take((size_t)B_N*S_LEN*H_DIM*2);
  f16* enc_ks  = (f16*)take((size_t)B_N*EK_ROWS*S_LEN*2);
  float* hTf = (float*)take((size_t)B_N*HH*4);
  float* cTf = (float*)take((size_t)B_N*HH*4);
  float* hTb = (float*)take((size_t)B_N*HH*4);
  float* cTb = (float*)take((size_t)B_N*HH*4);
  f16* Hbuf16 = (f16*)take((size_t)T_LEN*B_N*H_DIM*2);
  float* outp = (float*)d_out;

  auto prep = [&](u16* dst, const float* src, int K, int C, int sk, int sc){
    int n = K*C;
    k_prep<<<(n+255)/256, 256, 0, stream>>>(dst, src, K, C, sk, sc);
  };
  prep(wihF, Wih_f, 64, 400, 1, 64);
  prep(whhF, Whh_f, 100, 400, 1, 100);
  prep(wihB, Wih_b, 64, 400, 1, 64);
  prep(whhB, Whh_b, 100, 400, 1, 100);

  {
    int n;
    n = NCOL_PAD*KH_PAD; k_zf16<<<(n+255)/256,256,0,stream>>>(wattn16, n);
    n = NCOL_PAD*KC_PAD; k_zf16<<<(n+255)/256,256,0,stream>>>(wav16, n);
    n = 800*440; k_pack16<<<(n+255)/256,256,0,stream>>>(wall16, Wih_d, KTOT, 0,   800, 440, 1, 440);
    n = 800*200; k_pack16<<<(n+255)/256,256,0,stream>>>(wall16, Whh_d, KTOT, 440, 800, 200, 1, 200);
    n = 200*200; k_pack16<<<(n+255)/256,256,0,stream>>>(wattn16, W_attn, KH_PAD, 0, 200, 200, 200, 1);
    n = 200*400; k_pack16<<<(n+255)/256,256,0,stream>>>(wav16, W_av, KC_PAD, 0, 200, 400, 1, 400);
  }

  k_encoder<<<256, 512, 0, stream>>>(sentences, src_emb, b_f, b_b,
      (const uint2*)wihF, (const uint2*)whhF, (const uint2*)wihB, (const uint2*)whhB,
      enc_sk, hTf, cTf, hTb, cTb);

  k_transpose<<<B_N, 256, 0, stream>>>(enc_sk, enc_ks);

  k_decoder<<<128, 512, 0, stream>>>(is_prod, prod_ids, prim_ids, field_ids, parent_t,
      actprod, prim_emb, field_emb, b_d,
      wall16, wattn16, wav16,
      enc_ks, hTf, cTf, hTb, cTb, Hbuf16, outp);
}

// Round 4
// 6672.793 us; speedup vs baseline: 1.6523x; 1.1760x over previous
//
#include <hip/hip_runtime.h>

#define S_LEN 128
#define B_N   1024
#define T_LEN 96
#define E_DIM 64
#define HH    100
#define H_DIM 200
#define ACT_D 32
#define FLD_D 8
#define ATT_D 200
#define DEC_IN 440          // 32 + 200 + 8 + 200
#define KTOT  640           // DEC_IN + H_DIM
#define G4H   800           // 4*H
#define G4HH  400           // 4*HH
#define KH_PAD 224          // j-pad (7*32) for attGEMM
#define KC_PAD 416          // [ctx|h] k-pad for s_att MFMA
#define NCOL_PAD 208        // 13*16 col pad
#define EK_ROWS 208         // k-major row count (13*16)
// decoder LDS strides (f16 elems)
#define XA_LD 648
#define HG_LD 232
#define CAT_LD 424

typedef unsigned int  u32;
typedef unsigned short u16;
typedef _Float16 f16;
typedef _Float16 f16x8 __attribute__((ext_vector_type(8)));
typedef _Float16 f16x4 __attribute__((ext_vector_type(4)));
typedef float    f32x4 __attribute__((ext_vector_type(4)));

#define MFMA16(a,b,c) __builtin_amdgcn_mfma_f32_16x16x32_f16((a),(b),(c),0,0,0)

static __device__ __forceinline__ float lo_bf(u32 u){ union{u32 i; float f;}v; v.i = u<<16; return v.f; }
static __device__ __forceinline__ float hi_bf(u32 u){ union{u32 i; float f;}v; v.i = u & 0xffff0000u; return v.f; }
static __device__ __forceinline__ float sigf(float x){
  x = fminf(30.f, fmaxf(-30.f, x));
  return 1.f/(1.f + __expf(-x));
}
static __device__ __forceinline__ float tanhf_(float x){
  x = fminf(15.f, fmaxf(-15.f, x));
  float e = __expf(-2.f*x);
  return (1.f - e)/(1.f + e);
}

// ---------- prep kernels ----------
static __device__ __forceinline__ u16 f2bf(float f){
  union{float f; u32 i;} v; v.f = f;
  u32 r = v.i + 0x7fffu + ((v.i >> 16) & 1u);
  return (u16)(r >> 16);
}
__global__ void k_prep(u16* __restrict__ dst, const float* __restrict__ src,
                       int K, int C, int sk, int sc)
{
  int idx = blockIdx.x*256 + threadIdx.x;
  if (idx >= K*C) return;
  int k = idx / C, c = idx - k*C;
  dst[(size_t)(k>>2)*(4*C) + 4*c + (k&3)] = f2bf(src[(size_t)k*sk + (size_t)c*sc]);
}

__global__ void k_pack16(f16* __restrict__ dst, const float* __restrict__ src,
                         int Kld, int koff, int C, int K, int sk, int sc)
{
  int idx = blockIdx.x*256 + threadIdx.x;
  if (idx >= C*K) return;
  int c = idx / K, k = idx - c*K;
  dst[(size_t)c*Kld + koff + k] = (f16)src[(size_t)k*sk + (size_t)c*sc];
}

__global__ void k_zf16(f16* __restrict__ dst, int n)
{
  int idx = blockIdx.x*256 + threadIdx.x;
  if (idx < n) dst[idx] = (f16)0.f;
}

// Transpose enc_sk[b][s][200] -> enc_ks[b][k][128]; one block per b.
__global__ __launch_bounds__(256) void k_transpose(
    const f16* __restrict__ enc_sk, f16* __restrict__ enc_ks)
{
  __shared__ f16 ld[H_DIM][136];
  const int b = blockIdx.x, tid = threadIdx.x;
  const f16* src = enc_sk + (size_t)b*S_LEN*H_DIM;
  for (int idx = tid; idx < S_LEN*(H_DIM/4); idx += 256) {
    int s = idx / (H_DIM/4), jc = idx - s*(H_DIM/4);
    f16x4 v = *(const f16x4*)(src + (size_t)s*H_DIM + 4*jc);
    #pragma unroll
    for (int i = 0; i < 4; ++i) ld[4*jc + i][s] = v[i];
  }
  __syncthreads();
  f16* dst = enc_ks + (size_t)b*EK_ROWS*S_LEN;
  for (int idx = tid; idx < H_DIM*(S_LEN/8); idx += 256) {
    int k = idx / (S_LEN/8), so = idx - k*(S_LEN/8);
    f16x8 v;
    #pragma unroll
    for (int i = 0; i < 8; ++i) v[i] = ld[k][8*so + i];
    *(f16x8*)(dst + (size_t)k*S_LEN + 8*so) = v;
  }
}

// enc_att[b][n][s] = sum_j enc_sk[b][s][j] * W_attn[n][j]  (k-major output)
// One block per b. wattnT[c][j] = W_attn[c][j], rows c>=200 zero, j padded to 224.
__global__ __launch_bounds__(512) void k_attgemm(
    const f16* __restrict__ enc_sk, const f16* __restrict__ wattnT,
    f16* __restrict__ enc_att)
{
  __shared__ alignas(16) f16 et[S_LEN][KH_PAD];   // 57 KB
  const int b = blockIdx.x, tid = threadIdx.x;
  const int lane = tid & 63, wid = tid >> 6;
  const int arow = lane & 15, aoff = (lane >> 4) * 8;
  const f16* src = enc_sk + (size_t)b*S_LEN*H_DIM;
  for (int idx = tid; idx < S_LEN*(H_DIM/8); idx += 512) {
    int s = idx / (H_DIM/8), jo = idx - s*(H_DIM/8);
    *(f16x8*)&et[s][8*jo] = *(const f16x8*)(src + (size_t)s*H_DIM + 8*jo);
  }
  for (int idx = tid; idx < S_LEN*3; idx += 512) {     // pad j 200..223
    int s = idx / 3, jo = idx - s*3;
    *(f16x8*)&et[s][H_DIM + 8*jo] = (f16x8){0,0,0,0,0,0,0,0};
  }
  __syncthreads();
  f16x8 af[7];
  #pragma unroll
  for (int kk = 0; kk < 7; ++kk)
    af[kk] = *(const f16x8*)&et[wid*16 + arow][kk*32 + aoff];
  f16* dstb = enc_att + (size_t)b*EK_ROWS*S_LEN;
  for (int tt = 0; tt < 13; ++tt) {
    int c = tt*16 + arow;
    f32x4 acc = {0.f,0.f,0.f,0.f};
    const f16* p = wattnT + (size_t)c*KH_PAD + aoff;
    #pragma unroll
    for (int kk = 0; kk < 7; ++kk)
      acc = MFMA16(af[kk], *(const f16x8*)(p + kk*32), acc);
    int srow = wid*16 + (lane >> 4)*4;
    f16x4 v;
    #pragma unroll
    for (int i = 0; i < 4; ++i) v[i] = (f16)acc[i];
    *(f16x4*)(dstb + (size_t)c*S_LEN + srow) = v;
  }
}

// ---------- Bi-LSTM encoder ----------
__global__ __launch_bounds__(512) void k_encoder(
    const int* __restrict__ sentences, const float* __restrict__ src_emb,
    const float* __restrict__ b_f, const float* __restrict__ b_b,
    const uint2* __restrict__ wihF, const uint2* __restrict__ whhF,
    const uint2* __restrict__ wihB, const uint2* __restrict__ whhB,
    f16* __restrict__ enc_sk,              // [B][S][200] f16
    float* __restrict__ hTf, float* __restrict__ cTf,
    float* __restrict__ hTb, float* __restrict__ cTb)
{
  const int tid = threadIdx.x;
  const int dir = blockIdx.x >> 7;
  const int bg  = blockIdx.x & 127;
  const int b0  = bg * 8;

  __shared__ alignas(16) float xs[8][E_DIM];
  __shared__ alignas(16) float hs[8][HH];
  __shared__ alignas(16) float zs[8][G4HH];

  const uint2* wih = dir ? wihB : wihF;
  const uint2* whh = dir ? whhB : whhF;
  const float* bias = dir ? b_b : b_f;

  for (int idx = tid; idx < 8*HH; idx += 512) ((float*)hs)[idx] = 0.f;
  float c0r = 0.f, c1r = 0.f;

  const int col = tid;
  const bool act = (col < G4HH);
  const float bias0 = act ? bias[col] : 0.f;

  __syncthreads();

  for (int step = 0; step < S_LEN; ++step) {
    const int s = dir ? (S_LEN-1-step) : step;
    {
      int r = tid >> 6, e = tid & 63;
      int tok = sentences[s*B_N + (b0 + r)];
      xs[r][e] = src_emb[(size_t)tok*E_DIM + e];
    }
    __syncthreads();

    if (act) {
      float acc[8];
      #pragma unroll
      for (int r = 0; r < 8; ++r) acc[r] = bias0;
      #pragma unroll 2
      for (int k4 = 0; k4 < E_DIM/4; ++k4) {
        uint2 u = wih[k4*G4HH + col];
        float w0 = lo_bf(u.x), w1 = hi_bf(u.x), w2 = lo_bf(u.y), w3 = hi_bf(u.y);
        #pragma unroll
        for (int r = 0; r < 8; ++r) {
          float4 xv = *(const float4*)&xs[r][4*k4];
          acc[r] += xv.x*w0 + xv.y*w1 + xv.z*w2 + xv.w*w3;
        }
      }
      #pragma unroll 2
      for (int k4 = 0; k4 < HH/4; ++k4) {
        uint2 u = whh[k4*G4HH + col];
        float w0 = lo_bf(u.x), w1 = hi_bf(u.x), w2 = lo_bf(u.y), w3 = hi_bf(u.y);
        #pragma unroll
        for (int r = 0; r < 8; ++r) {
          float4 hv = *(const float4*)&hs[r][4*k4];
          acc[r] += hv.x*w0 + hv.y*w1 + hv.z*w2 + hv.w*w3;
        }
      }
      #pragma unroll
      for (int r = 0; r < 8; ++r) zs[r][col] = acc[r];
    }
    __syncthreads();

    {
      int r = tid / HH, j = tid - r*HH;
      float c = sigf(zs[r][HH+j])*c0r + sigf(zs[r][j])*tanhf_(zs[r][2*HH+j]);
      float h = sigf(zs[r][3*HH+j])*tanhf_(c);
      c0r = c;
      hs[r][j] = h;
      enc_sk[((size_t)(b0+r)*S_LEN + s)*H_DIM + dir*HH + j] = (f16)h;
      if (tid < 8*HH - 512) {
        int idx2 = tid + 512;
        int r2 = idx2 / HH, j2 = idx2 - r2*HH;
        float c2 = sigf(zs[r2][HH+j2])*c1r + sigf(zs[r2][j2])*tanhf_(zs[r2][2*HH+j2]);
        float h2 = sigf(zs[r2][3*HH+j2])*tanhf_(c2);
        c1r = c2;
        hs[r2][j2] = h2;
        enc_sk[((size_t)(b0+r2)*S_LEN + s)*H_DIM + dir*HH + j2] = (f16)h2;
      }
    }
    __syncthreads();
  }

  float* hT = dir ? hTb : hTf;
  float* cT = dir ? cTb : cTf;
  {
    int r = tid / HH, j = tid - r*HH;
    hT[(b0+r)*HH + j] = hs[r][j];
    cT[(b0+r)*HH + j] = c0r;
    if (tid < 8*HH - 512) {
      int idx2 = tid + 512; int r2 = idx2 / HH, j2 = idx2 - r2*HH;
      hT[(b0+r2)*HH + j2] = hs[r2][j2];
      cT[(b0+r2)*HH + j2] = c1r;
    }
  }
}

// ---------- Decoder: 4 rows/block, 256 blocks, 5 barriers/step ----------
__global__ __launch_bounds__(512, 2) void k_decoder(
  const int* __restrict__ is_prod, const int* __restrict__ prod_ids,
  const int* __restrict__ prim_ids, const int* __restrict__ field_ids,
  const int* __restrict__ parent_t,
  const float* __restrict__ actprod_emb, const float* __restrict__ prim_emb,
  const float* __restrict__ field_emb, const float* __restrict__ b_d,
  const f16* __restrict__ wall,    // [800][640]
  const f16* __restrict__ wav,     // [208][416]
  const f16* __restrict__ enc_ks,  // [B][208][128]
  const f16* __restrict__ enc_att, // [B][208][128]
  const float* __restrict__ hTf, const float* __restrict__ cTf,
  const float* __restrict__ hTb, const float* __restrict__ cTb,
  f16* __restrict__ Hbuf, float* __restrict__ out)
{
  const int tid  = threadIdx.x;
  const int lane = tid & 63;
  const int wid  = tid >> 6;          // 8 waves
  const int b0   = blockIdx.x * 4;
  const int arow = lane & 15;
  const int aoff = (lane >> 4) * 8;

  __shared__ alignas(16) f16   xa[4][XA_LD];    // [a32|s_att200|nft8|parent200|h200]
  __shared__ alignas(16) f16   hg[4][HG_LD];    // h (zero-padded to 232)
  __shared__ alignas(16) f16   cat[4][CAT_LD];  // [ctx200|h200|pad16]
  __shared__ alignas(16) f16   aw_sh[4][S_LEN];
  __shared__ alignas(16) float zs[4][G4H];
  __shared__ float biasd[G4H];

  // ---- init
  for (int idx = tid; idx < G4H; idx += 512) biasd[idx] = b_d[idx];
  for (int idx = tid; idx < 4*(HG_LD-H_DIM); idx += 512) {
    int n = HG_LD-H_DIM; hg[idx/n][H_DIM + idx%n] = (f16)0.f;
  }
  for (int idx = tid; idx < 4*(CAT_LD-2*H_DIM); idx += 512) {
    int n = CAT_LD-2*H_DIM; cat[idx/n][2*H_DIM + idx%n] = (f16)0.f;
  }
  for (int idx = tid; idx < 4*DEC_IN; idx += 512) {   // t=0 input = zeros
    xa[idx/DEC_IN][idx%DEC_IN] = (f16)0.f;
  }
  for (int idx = tid; idx < 4*H_DIM; idx += 512) {
    int r = idx / H_DIM, j = idx - r*H_DIM; int b = b0 + r;
    float v;
    if (b < 512) v = (j < HH) ? hTf[(2*b)*HH + j] : hTf[(2*b+1)*HH + (j-HH)];
    else { int bb = b-512; v = (j < HH) ? hTb[(2*bb)*HH + j] : hTb[(2*bb+1)*HH + (j-HH)]; }
    f16 hv = (f16)v;
    xa[r][DEC_IN + j] = hv; hg[r][j] = hv; cat[r][H_DIM + j] = hv;
  }
  float cst[2] = {0.f, 0.f};
  #pragma unroll
  for (int kk = 0; kk < 2; ++kk) {
    int slot = tid + 512*kk;
    if (slot < 4*H_DIM) {
      int r = slot / H_DIM, j = slot - r*H_DIM; int b = b0 + r;
      float v;
      if (b < 512) v = (j < HH) ? cTf[(2*b)*HH + j] : cTf[(2*b+1)*HH + (j-HH)];
      else { int bb = b-512; v = (j < HH) ? cTb[(2*bb)*HH + j] : cTb[(2*bb+1)*HH + (j-HH)]; }
      cst[kk] = v;
    }
  }
  __syncthreads();

  for (int t = 0; t < T_LEN; ++t) {
    // ---- z = [inp|h] @ wall + b_d via MFMA (20 k-tiles, 50 n-tiles over 8 waves)
    {
      f16x8 afr[20];
      #pragma unroll
      for (int kk = 0; kk < 20; ++kk) {
        f16x8 v = {0,0,0,0,0,0,0,0};
        if (arow < 4) v = *(const f16x8*)&xa[arow][kk*32 + aoff];
        afr[kk] = v;
      }
      for (int tt = wid; tt < 50; tt += 8) {
        int c = tt*16 + arow;
        float bv = biasd[c];
        f32x4 acc = {bv, bv, bv, bv};
        const f16* p = wall + (size_t)c*KTOT + aoff;
        #pragma unroll
        for (int kk = 0; kk < 20; ++kk)
          acc = MFMA16(afr[kk], *(const f16x8*)(p + kk*32), acc);
        if (lane < 16) {      // C rows 0-3 (quad 0)
          #pragma unroll
          for (int i2 = 0; i2 < 4; ++i2) zs[i2][c] = acc[i2];
        }
      }
    }
    __syncthreads();

    // ---- LSTM cell (i,f,g,o)
    #pragma unroll
    for (int kk = 0; kk < 2; ++kk) {
      int slot = tid + 512*kk;
      if (slot < 4*H_DIM) {
        int r = slot / H_DIM, j = slot - r*H_DIM;
        float c = sigf(zs[r][H_DIM+j])*cst[kk] + sigf(zs[r][j])*tanhf_(zs[r][2*H_DIM+j]);
        float h = sigf(zs[r][3*H_DIM+j])*tanhf_(c);
        cst[kk] = c;
        f16 hv = (f16)h;
        xa[r][DEC_IN + j] = hv; hg[r][j] = hv; cat[r][H_DIM + j] = hv;
        Hbuf[((size_t)t*B_N + (b0+r))*H_DIM + j] = hv;
      }
    }
    __syncthreads();

    // ---- scores + softmax: waves 0-3, one per row; lanes = 16 s-octets x 4 k-parts
    if (wid < 4) {
      const int r = wid;
      const int sl = lane & 15, kp = lane >> 4;
      const f16* ep = enc_att + ((size_t)(b0+r)*EK_ROWS + kp*52)*S_LEN + 8*sl;
      const f16* hp = &hg[r][kp*52];
      float acc[8] = {0.f,0.f,0.f,0.f,0.f,0.f,0.f,0.f};
      #pragma unroll 4
      for (int i = 0; i < 52; ++i) {
        f16x8 e8 = *(const f16x8*)(ep + (size_t)i*S_LEN);
        float hf = (float)hp[i];
        #pragma unroll
        for (int q = 0; q < 8; ++q) acc[q] += hf * (float)e8[q];
      }
      #pragma unroll
      for (int q = 0; q < 8; ++q) {
        acc[q] += __shfl_xor(acc[q], 16);
        acc[q] += __shfl_xor(acc[q], 32);
      }
      float m = acc[0];
      #pragma unroll
      for (int q = 1; q < 8; ++q) m = fmaxf(m, acc[q]);
      #pragma unroll
      for (int d = 1; d < 16; d <<= 1) m = fmaxf(m, __shfl_xor(m, d));
      float e[8], sm = 0.f;
      #pragma unroll
      for (int q = 0; q < 8; ++q) { e[q] = __expf(acc[q] - m); sm += e[q]; }
      #pragma unroll
      for (int d = 1; d < 16; d <<= 1) sm += __shfl_xor(sm, d);
      float rd = 1.f / sm;
      if (kp == 0) {
        f16x8 w;
        #pragma unroll
        for (int q = 0; q < 8; ++q) w[q] = (f16)(e[q] * rd);
        *(f16x8*)&aw_sh[r][8*sl] = w;
      }
    }
    __syncthreads();

    // ---- ctx via block-diagonal MFMA (K'=(r',s)=512, 13 n-tiles) + stage t+1
    {
      #pragma unroll
      for (int pass = 0; pass < 2; ++pass) {
        int tt = wid + pass*8;
        if (tt < 13) {
          int c = tt*16 + arow;
          f32x4 acc = {0.f,0.f,0.f,0.f};
          const f16* eb = enc_ks + (size_t)b0*EK_ROWS*S_LEN + (size_t)c*S_LEN + aoff;
          #pragma unroll 4
          for (int kt = 0; kt < 16; ++kt) {
            int rp = kt >> 2;
            int s0 = (kt & 3) * 32;
            f16x8 a = {0,0,0,0,0,0,0,0};
            if (arow == rp) a = *(const f16x8*)&aw_sh[rp][s0 + aoff];
            f16x8 bf = *(const f16x8*)(eb + (size_t)rp*EK_ROWS*S_LEN + s0);
            acc = MFMA16(a, bf, acc);
          }
          if (lane < 16 && c < H_DIM) {
            #pragma unroll
            for (int i2 = 0; i2 < 4; ++i2) cat[i2][c] = (f16)acc[i2];
          }
        }
      }
      // stage a/nft/parent for step t+1 (regions disjoint from s_att/h)
      if (t + 1 < T_LEN) {
        const int tn = t + 1;
        for (int idx = tid; idx < 4*DEC_IN; idx += 512) {
          int r = idx / DEC_IN, k = idx - r*DEC_IN;
          if (k >= ACT_D && k < ACT_D + ATT_D) continue;
          int b = b0 + r;
          f16 v;
          if (k < ACT_D) {
            float f = (is_prod[tn*B_N + b] == 1)
              ? actprod_emb[prod_ids[tn*B_N + b]*ACT_D + k]
              : prim_emb[prim_ids[tn*B_N + b]*ACT_D + k];
            v = (f16)f;
          } else if (k < ACT_D + ATT_D + FLD_D) {
            v = (f16)field_emb[field_ids[tn*B_N + b]*FLD_D + (k - ACT_D - ATT_D)];
          } else {
            int pt = parent_t[tn*B_N + b];
            v = Hbuf[((size_t)pt*B_N + b)*H_DIM + (k - (ACT_D+ATT_D+FLD_D))];
          }
          xa[r][k] = v;
        }
      }
    }
    __syncthreads();

    // ---- s_att = tanh([ctx|h] @ wav) via MFMA (13 k-tiles, 13 n-tiles)
    {
      f16x8 sa[13];
      #pragma unroll
      for (int kk = 0; kk < 13; ++kk) {
        f16x8 v = {0,0,0,0,0,0,0,0};
        if (arow < 4) v = *(const f16x8*)&cat[arow][kk*32 + aoff];
        sa[kk] = v;
      }
      #pragma unroll
      for (int pass = 0; pass < 2; ++pass) {
        int tt = wid + pass*8;
        if (tt < 13) {
          int c = tt*16 + arow;
          f32x4 acc = {0.f,0.f,0.f,0.f};
          const f16* p = wav + (size_t)c*KC_PAD + aoff;
          #pragma unroll
          for (int kk = 0; kk < 13; ++kk)
            acc = MFMA16(sa[kk], *(const f16x8*)(p + kk*32), acc);
          if (lane < 16 && c < ATT_D) {
            #pragma unroll
            for (int i2 = 0; i2 < 4; ++i2) {
              float v = tanhf_(acc[i2]);
              out[((size_t)t*B_N + (b0+i2))*ATT_D + c] = v;
              xa[i2][ACT_D + c] = (f16)v;
            }
          }
        }
      }
    }
    __syncthreads();
  }
}

extern "C" void kernel_launch(void* const* d_in, const int* in_sizes, int n_in,
                              void* d_out, int out_size, void* d_ws, size_t ws_size,
                              hipStream_t stream)
{
  const int*   sentences = (const int*)  d_in[0];
  const int*   is_prod   = (const int*)  d_in[1];
  const int*   prod_ids  = (const int*)  d_in[2];
  const int*   prim_ids  = (const int*)  d_in[3];
  const int*   field_ids = (const int*)  d_in[4];
  const int*   parent_t  = (const int*)  d_in[5];
  const float* src_emb   = (const float*)d_in[6];
  const float* actprod   = (const float*)d_in[7];
  const float* prim_emb  = (const float*)d_in[8];
  const float* field_emb = (const float*)d_in[9];
  const float* Wih_f = (const float*)d_in[10];
  const float* Whh_f = (const float*)d_in[11];
  const float* b_f   = (const float*)d_in[12];
  const float* Wih_b = (const float*)d_in[13];
  const float* Whh_b = (const float*)d_in[14];
  const float* b_b   = (const float*)d_in[15];
  const float* Wih_d = (const float*)d_in[16];
  const float* Whh_d = (const float*)d_in[17];
  const float* b_d   = (const float*)d_in[18];
  const float* W_attn= (const float*)d_in[19];
  const float* W_av  = (const float*)d_in[20];
  (void)in_sizes; (void)n_in; (void)out_size; (void)ws_size;

  char* ws = (char*)d_ws;
  size_t off = 0;
  auto take = [&](size_t bytes) -> void* {
    void* p = ws + off;
    off = (off + bytes + 255) & ~(size_t)255;
    return p;
  };
  u16* wihF = (u16*)take((size_t)64*400*2);
  u16* whhF = (u16*)take((size_t)100*400*2);
  u16* wihB = (u16*)take((size_t)64*400*2);
  u16* whhB = (u16*)take((size_t)100*400*2);
  f16* wall16  = (f16*)take((size_t)800*640*2);
  f16* wattnT  = (f16*)take((size_t)NCOL_PAD*KH_PAD*2);
  f16* wav16   = (f16*)take((size_t)NCOL_PAD*KC_PAD*2);
  f16* enc_sk  = (f16*)take((size_t)B_N*S_LEN*H_DIM*2);
  f16* enc_ks  = (f16*)take((size_t)B_N*EK_ROWS*S_LEN*2);
  f16* enc_att = (f16*)take((size_t)B_N*EK_ROWS*S_LEN*2);
  float* hTf = (float*)take((size_t)B_N*HH*4);
  float* cTf = (float*)take((size_t)B_N*HH*4);
  float* hTb = (float*)take((size_t)B_N*HH*4);
  float* cTb = (float*)take((size_t)B_N*HH*4);
  f16* Hbuf16 = (f16*)take((size_t)T_LEN*B_N*H_DIM*2);
  float* outp = (float*)d_out;

  auto prep = [&](u16* dst, const float* src, int K, int C, int sk, int sc){
    int n = K*C;
    k_prep<<<(n+255)/256, 256, 0, stream>>>(dst, src, K, C, sk, sc);
  };
  prep(wihF, Wih_f, 64, 400, 1, 64);
  prep(whhF, Whh_f, 100, 400, 1, 100);
  prep(wihB, Wih_b, 64, 400, 1, 64);
  prep(whhB, Whh_b, 100, 400, 1, 100);

  {
    int n;
    n = NCOL_PAD*KH_PAD; k_zf16<<<(n+255)/256,256,0,stream>>>(wattnT, n);
    n = NCOL_PAD*KC_PAD; k_zf16<<<(n+255)/256,256,0,stream>>>(wav16, n);
    n = 800*440; k_pack16<<<(n+255)/256,256,0,stream>>>(wall16, Wih_d, KTOT, 0,   800, 440, 1, 440);
    n = 800*200; k_pack16<<<(n+255)/256,256,0,stream>>>(wall16, Whh_d, KTOT, 440, 800, 200, 1, 200);
    // wattnT[c][j] = W_attn[c][j]
    n = 200*200; k_pack16<<<(n+255)/256,256,0,stream>>>(wattnT, W_attn, KH_PAD, 0, 200, 200, 1, 200);
    // wav[c][k] = W_av[c? ] : B[k][n]=W_av[n][k] -> dst[c*KC+k]=W_av[k... src[k*1 + c*400]
    n = 200*400; k_pack16<<<(n+255)/256,256,0,stream>>>(wav16, W_av, KC_PAD, 0, 200, 400, 1, 400);
  }

  k_encoder<<<256, 512, 0, stream>>>(sentences, src_emb, b_f, b_b,
      (const uint2*)wihF, (const uint2*)whhF, (const uint2*)wihB, (const uint2*)whhB,
      enc_sk, hTf, cTf, hTb, cTb);

  k_transpose<<<B_N, 256, 0, stream>>>(enc_sk, enc_ks);
  k_attgemm<<<B_N, 512, 0, stream>>>(enc_sk, wattnT, enc_att);

  k_decoder<<<256, 512, 0, stream>>>(is_prod, prod_ids, prim_ids, field_ids, parent_t,
      actprod, prim_emb, field_emb, b_d,
      wall16, wav16,
      enc_ks, enc_att, hTf, cTf, hTb, cTb, Hbuf16, outp);
}